// Round 4
// baseline (4523.442 us; speedup 1.0000x reference)
//
#include <hip/hip_runtime.h>

// N=100000 nodes, E=1250000 edges, all dims 64. fp32 end-to-end.
// R4: layer kernels were LDS-pipe-bound, ~80% of LDS bytes = per-node weight
// re-reads (20KB/node). Now each wave owns 4 nodes: gather sequentially,
// stage to a private LDS slot (wave-local, no barrier), then GEMM/LN/proj
// with every weight ds_read_b128 reused 4x.

#define SCAN_CHUNK 2048

__global__ void k_count(const int* __restrict__ ei, int E, int* __restrict__ cnt) {
    int i = blockIdx.x * blockDim.x + threadIdx.x;
    int e = i * 4;
    if (e + 4 <= E) {
        int4 d = *(const int4*)&ei[E + e];
        atomicAdd(&cnt[d.x], 1); atomicAdd(&cnt[d.y], 1);
        atomicAdd(&cnt[d.z], 1); atomicAdd(&cnt[d.w], 1);
    } else {
        for (int j = e; j < E; ++j) atomicAdd(&cnt[ei[E + j]], 1);
    }
}

__global__ void k_scan_reduce(const int* __restrict__ cnt, int N, int* __restrict__ blockSums) {
    __shared__ int lds[256];
    int base = blockIdx.x * SCAN_CHUNK;
    int t = threadIdx.x;
    int s = 0;
    for (int j = 0; j < 8; ++j) {
        int idx = base + t * 8 + j;
        if (idx < N) s += cnt[idx];
    }
    lds[t] = s;
    __syncthreads();
    for (int d = 128; d > 0; d >>= 1) {
        if (t < d) lds[t] += lds[t + d];
        __syncthreads();
    }
    if (t == 0) blockSums[blockIdx.x] = lds[0];
}

__global__ void k_scan_spine(int* __restrict__ blockSums, int B) {
    if (threadIdx.x == 0 && blockIdx.x == 0) {
        int run = 0;
        for (int b = 0; b < B; ++b) { int v = blockSums[b]; blockSums[b] = run; run += v; }
    }
}

__global__ void k_scan_write(const int* __restrict__ cnt, int N,
                             const int* __restrict__ blockSums,
                             int* __restrict__ offs, float* __restrict__ dinv) {
    __shared__ int lds[256];
    int base = blockIdx.x * SCAN_CHUNK;
    int t = threadIdx.x;
    int v[8];
    int s = 0;
    for (int j = 0; j < 8; ++j) {
        int idx = base + t * 8 + j;
        v[j] = (idx < N) ? cnt[idx] : 0;
        s += v[j];
    }
    lds[t] = s;
    __syncthreads();
    for (int d = 1; d < 256; d <<= 1) {
        int x = (t >= d) ? lds[t - d] : 0;
        __syncthreads();
        lds[t] += x;
        __syncthreads();
    }
    int excl = (t == 0) ? 0 : lds[t - 1];
    int run = blockSums[blockIdx.x] + excl;
    for (int j = 0; j < 8; ++j) {
        int idx = base + t * 8 + j;
        if (idx < N) {
            offs[idx] = run;
            run += v[j];
            dinv[idx] = rsqrtf((float)v[j] + 1.0f);
        }
    }
}

__global__ void k_fill(const int* __restrict__ ei, int E, const int* __restrict__ offs,
                       int* __restrict__ cursor, int* __restrict__ csr) {
    int i = blockIdx.x * blockDim.x + threadIdx.x;
    int e = i * 4;
    if (e + 4 <= E) {
        int4 s = *(const int4*)&ei[e];
        int4 d = *(const int4*)&ei[E + e];
        csr[offs[d.x] + atomicAdd(&cursor[d.x], 1)] = s.x;
        csr[offs[d.y] + atomicAdd(&cursor[d.y], 1)] = s.y;
        csr[offs[d.z] + atomicAdd(&cursor[d.z], 1)] = s.z;
        csr[offs[d.w] + atomicAdd(&cursor[d.w], 1)] = s.w;
    } else {
        for (int j = e; j < E; ++j) {
            int s = ei[j], d = ei[E + j];
            csr[offs[d] + atomicAdd(&cursor[d], 1)] = s;
        }
    }
}

__device__ __forceinline__ void xor_reduce8(float4& a, float4& b) {
    a.x += __shfl_xor(a.x, 16, 64); a.y += __shfl_xor(a.y, 16, 64);
    a.z += __shfl_xor(a.z, 16, 64); a.w += __shfl_xor(a.w, 16, 64);
    b.x += __shfl_xor(b.x, 16, 64); b.y += __shfl_xor(b.y, 16, 64);
    b.z += __shfl_xor(b.z, 16, 64); b.w += __shfl_xor(b.w, 16, 64);
    a.x += __shfl_xor(a.x, 32, 64); a.y += __shfl_xor(a.y, 32, 64);
    a.z += __shfl_xor(a.z, 32, 64); a.w += __shfl_xor(a.w, 32, 64);
    b.x += __shfl_xor(b.x, 32, 64); b.y += __shfl_xor(b.y, 32, 64);
    b.z += __shfl_xor(b.z, 32, 64); b.w += __shfl_xor(b.w, 32, 64);
}

// Layer 1: each wave gathers 4 nodes (x, GCN-weighted + SAGE-mean), stages
// (gin|sin|xv) per node into its LDS slot, then fused GEMMs with weights
// read once per 4 nodes. buf1[node] = (relu(g) | relu(s1)).
__launch_bounds__(1024)
__global__ void k_layer1_fused(const float* __restrict__ x, const int* __restrict__ csr,
                               const int* __restrict__ offs, const int* __restrict__ cnt,
                               const float* __restrict__ dinv,
                               const float* __restrict__ W1, const float* __restrict__ b1,
                               const float* __restrict__ Wl1, const float* __restrict__ bl1,
                               const float* __restrict__ Wr1,
                               float* __restrict__ buf1, int N) {
    __shared__ float sW1[64 * 68], sWl[64 * 68], sWr[64 * 68];  // 52.2 KB
    __shared__ float sS[16 * 4 * 192];                          // 48 KB
    int t = threadIdx.x;
    for (int i = t; i < 4096; i += 1024) {
        int k = i >> 6, o = i & 63;
        sW1[o * 68 + k] = W1[i];
        sWl[o * 68 + k] = Wl1[i];
        sWr[o * 68 + k] = Wr1[i];
    }
    __syncthreads();

    int lane = t & 63;
    int wave = t >> 6;
    int c = lane & 15, grp = lane >> 4;
    int wbase = wave * 768;
    int base_node = (blockIdx.x * 16 + wave) * 4;

    #pragma unroll
    for (int j = 0; j < 4; ++j) {
        int node = base_node + j;
        if (node >= N) break;
        int st = offs[node];
        int cn = cnt[node];
        float di = dinv[node];

        float4 aA = {0.f, 0.f, 0.f, 0.f}, aB = {0.f, 0.f, 0.f, 0.f};
        for (int e = 0; e < cn; e += 8) {
            int i0 = e + grp, i1 = e + 4 + grp;
            float m0 = (i0 < cn) ? 1.f : 0.f;
            float m1 = (i1 < cn) ? 1.f : 0.f;
            int s0 = csr[st + (i0 < cn ? i0 : cn - 1)];
            int s1 = csr[st + (i1 < cn ? i1 : cn - 1)];
            float w0 = m0 * dinv[s0];
            float w1 = m1 * dinv[s1];
            float4 v0 = *(const float4*)&x[(size_t)s0 * 64 + 4 * c];
            float4 v1 = *(const float4*)&x[(size_t)s1 * 64 + 4 * c];
            aA.x += w0 * v0.x + w1 * v1.x; aA.y += w0 * v0.y + w1 * v1.y;
            aA.z += w0 * v0.z + w1 * v1.z; aA.w += w0 * v0.w + w1 * v1.w;
            aB.x += m0 * v0.x + m1 * v1.x; aB.y += m0 * v0.y + m1 * v1.y;
            aB.z += m0 * v0.z + m1 * v1.z; aB.w += m0 * v0.w + m1 * v1.w;
        }
        xor_reduce8(aA, aB);

        float4 selfq = *(const float4*)&x[(size_t)node * 64 + 4 * c];
        float4 val;
        if (grp == 0) {
            float d2 = di * di;
            val.x = di * aA.x + d2 * selfq.x; val.y = di * aA.y + d2 * selfq.y;
            val.z = di * aA.z + d2 * selfq.z; val.w = di * aA.w + d2 * selfq.w;
        } else if (grp == 1) {
            float rn = 1.0f / fmaxf((float)cn, 1.0f);
            val.x = aB.x * rn; val.y = aB.y * rn; val.z = aB.z * rn; val.w = aB.w * rn;
        } else {
            val = selfq;  // xv (grp==2); grp==3 masked off
        }
        if (grp < 3) *(float4*)&sS[wbase + j * 192 + grp * 64 + 4 * c] = val;
    }
    // wave-local LDS dependency only; compiler emits lgkmcnt waits. No barrier.

    float bg = b1[lane], bs = bl1[lane];
    float accG[4] = {bg, bg, bg, bg};
    float accS[4] = {bs, bs, bs, bs};
    #pragma unroll
    for (int kq = 0; kq < 16; ++kq) {
        float4 w1 = *(const float4*)&sW1[lane * 68 + 4 * kq];
        float4 wl = *(const float4*)&sWl[lane * 68 + 4 * kq];
        float4 wr = *(const float4*)&sWr[lane * 68 + 4 * kq];
        #pragma unroll
        for (int j = 0; j < 4; ++j) {
            const float* slot = &sS[wbase + j * 192];
            float4 ia = *(const float4*)&slot[4 * kq];
            float4 ib = *(const float4*)&slot[64 + 4 * kq];
            float4 ic = *(const float4*)&slot[128 + 4 * kq];
            accG[j] += ia.x * w1.x + ia.y * w1.y + ia.z * w1.z + ia.w * w1.w;
            accS[j] += ib.x * wl.x + ib.y * wl.y + ib.z * wl.z + ib.w * wl.w
                     + ic.x * wr.x + ic.y * wr.y + ic.z * wr.z + ic.w * wr.w;
        }
    }
    #pragma unroll
    for (int j = 0; j < 4; ++j) {
        int node = base_node + j;
        if (node < N) {
            buf1[(size_t)node * 128 + lane]      = fmaxf(accG[j], 0.f);
            buf1[(size_t)node * 128 + 64 + lane] = fmaxf(accS[j], 0.f);
        }
    }
}

// Layer 2: gather(g,s1) for 4 nodes/wave -> GEMMs -> LN -> concat-proj -> out.
__launch_bounds__(1024)
__global__ void k_layer2_fused(const float* __restrict__ gs, const int* __restrict__ csr,
                               const int* __restrict__ offs, const int* __restrict__ cnt,
                               const float* __restrict__ dinv,
                               const float* __restrict__ W2, const float* __restrict__ b2,
                               const float* __restrict__ Wl2, const float* __restrict__ bl2,
                               const float* __restrict__ Wr2,
                               const float* __restrict__ lngG, const float* __restrict__ lnbG,
                               const float* __restrict__ lngS, const float* __restrict__ lnbS,
                               const float* __restrict__ Pw, const float* __restrict__ Pb,
                               float* __restrict__ out, int N) {
    __shared__ float sW2[64 * 68], sWl[64 * 68], sWr[64 * 68];  // 52.2 KB
    __shared__ float sPt[64 * 132];                             // 33.8 KB
    __shared__ float sS[16 * 4 * 192];                          // 48 KB
    int t = threadIdx.x;
    for (int i = t; i < 4096; i += 1024) {
        int k = i >> 6, o = i & 63;
        sW2[o * 68 + k] = W2[i];
        sWl[o * 68 + k] = Wl2[i];
        sWr[o * 68 + k] = Wr2[i];
    }
    for (int i = t; i < 8192; i += 1024) {
        int k = i >> 6, o = i & 63;
        sPt[o * 132 + k] = Pw[i];
    }
    __syncthreads();

    int lane = t & 63;
    int wave = t >> 6;
    int c = lane & 15, grp = lane >> 4;
    int wbase = wave * 768;
    int base_node = (blockIdx.x * 16 + wave) * 4;

    #pragma unroll
    for (int j = 0; j < 4; ++j) {
        int node = base_node + j;
        if (node >= N) break;
        int st = offs[node];
        int cn = cnt[node];
        float di = dinv[node];

        float4 aC = {0.f, 0.f, 0.f, 0.f}, aD = {0.f, 0.f, 0.f, 0.f};
        for (int e = 0; e < cn; e += 8) {
            int i0 = e + grp, i1 = e + 4 + grp;
            float m0 = (i0 < cn) ? 1.f : 0.f;
            float m1 = (i1 < cn) ? 1.f : 0.f;
            int s0 = csr[st + (i0 < cn ? i0 : cn - 1)];
            int s1 = csr[st + (i1 < cn ? i1 : cn - 1)];
            float w0 = m0 * dinv[s0];
            float w1 = m1 * dinv[s1];
            const float* p0 = gs + (size_t)s0 * 128 + 4 * c;
            const float* p1 = gs + (size_t)s1 * 128 + 4 * c;
            float4 g0 = *(const float4*)p0;
            float4 g1 = *(const float4*)p1;
            float4 t0 = *(const float4*)(p0 + 64);
            float4 t1 = *(const float4*)(p1 + 64);
            aC.x += w0 * g0.x + w1 * g1.x; aC.y += w0 * g0.y + w1 * g1.y;
            aC.z += w0 * g0.z + w1 * g1.z; aC.w += w0 * g0.w + w1 * g1.w;
            aD.x += m0 * t0.x + m1 * t1.x; aD.y += m0 * t0.y + m1 * t1.y;
            aD.z += m0 * t0.z + m1 * t1.z; aD.w += m0 * t0.w + m1 * t1.w;
        }
        xor_reduce8(aC, aD);

        float4 selfq = *(const float4*)&gs[(size_t)node * 128 + (grp == 2 ? 64 : 0) + 4 * c];
        float4 val;
        if (grp == 0) {
            float d2 = di * di;
            val.x = di * aC.x + d2 * selfq.x; val.y = di * aC.y + d2 * selfq.y;
            val.z = di * aC.z + d2 * selfq.z; val.w = di * aC.w + d2 * selfq.w;
        } else if (grp == 1) {
            float rn = 1.0f / fmaxf((float)cn, 1.0f);
            val.x = aD.x * rn; val.y = aD.y * rn; val.z = aD.z * rn; val.w = aD.w * rn;
        } else {
            val = selfq;  // sv (grp==2); grp==3 masked off
        }
        if (grp < 3) *(float4*)&sS[wbase + j * 192 + grp * 64 + 4 * c] = val;
    }

    float accG[4], accS[4];
    #pragma unroll
    for (int j = 0; j < 4; ++j) { accG[j] = 0.f; accS[j] = 0.f; }
    #pragma unroll
    for (int kq = 0; kq < 16; ++kq) {
        float4 w2 = *(const float4*)&sW2[lane * 68 + 4 * kq];
        float4 wl = *(const float4*)&sWl[lane * 68 + 4 * kq];
        float4 wr = *(const float4*)&sWr[lane * 68 + 4 * kq];
        #pragma unroll
        for (int j = 0; j < 4; ++j) {
            const float* slot = &sS[wbase + j * 192];
            float4 ia = *(const float4*)&slot[4 * kq];
            float4 ib = *(const float4*)&slot[64 + 4 * kq];
            float4 ic = *(const float4*)&slot[128 + 4 * kq];
            accG[j] += ia.x * w2.x + ia.y * w2.y + ia.z * w2.z + ia.w * w2.w;
            accS[j] += ib.x * wl.x + ib.y * wl.y + ib.z * wl.z + ib.w * wl.w
                     + ic.x * wr.x + ic.y * wr.y + ic.z * wr.z + ic.w * wr.w;
        }
    }

    float bg = b2[lane], bs = bl2[lane];
    float gG = lngG[lane], bG = lnbG[lane], gS = lngS[lane], bS = lnbS[lane];

    #pragma unroll
    for (int j = 0; j < 4; ++j) {
        float aGv = accG[j] + bg;
        float aSv = accS[j] + bs;
        float sG = aGv, qG = aGv * aGv, sSs = aSv, qS = aSv * aSv;
        #pragma unroll
        for (int m = 1; m < 64; m <<= 1) {
            sG += __shfl_xor(sG, m, 64);
            qG += __shfl_xor(qG, m, 64);
            sSs += __shfl_xor(sSs, m, 64);
            qS += __shfl_xor(qS, m, 64);
        }
        float muG = sG * (1.0f / 64.0f);
        float varG = fmaxf(qG * (1.0f / 64.0f) - muG * muG, 0.0f);
        float muS = sSs * (1.0f / 64.0f);
        float varS = fmaxf(qS * (1.0f / 64.0f) - muS * muS, 0.0f);
        float gln = (aGv - muG) * rsqrtf(varG + 1e-5f) * gG + bG;
        float sln = (aSv - muS) * rsqrtf(varS + 1e-5f) * gS + bS;
        sS[wbase + j * 192 + lane] = gln;
        sS[wbase + j * 192 + 64 + lane] = sln;
    }

    float accO[4];
    float pb = Pb[lane];
    #pragma unroll
    for (int j = 0; j < 4; ++j) accO[j] = pb;
    #pragma unroll
    for (int kq = 0; kq < 16; ++kq) {
        float4 p0 = *(const float4*)&sPt[lane * 132 + 4 * kq];
        float4 p1 = *(const float4*)&sPt[lane * 132 + 64 + 4 * kq];
        #pragma unroll
        for (int j = 0; j < 4; ++j) {
            const float* slot = &sS[wbase + j * 192];
            float4 u0 = *(const float4*)&slot[4 * kq];
            float4 u1 = *(const float4*)&slot[64 + 4 * kq];
            accO[j] += u0.x * p0.x + u0.y * p0.y + u0.z * p0.z + u0.w * p0.w
                     + u1.x * p1.x + u1.y * p1.y + u1.z * p1.z + u1.w * p1.w;
        }
    }
    #pragma unroll
    for (int j = 0; j < 4; ++j) {
        int node = base_node + j;
        if (node < N) out[(size_t)node * 64 + lane] = accO[j];
    }
}

extern "C" void kernel_launch(void* const* d_in, const int* in_sizes, int n_in,
                              void* d_out, int out_size, void* d_ws, size_t ws_size,
                              hipStream_t stream) {
    const float* x        = (const float*)d_in[0];
    const int*   ei       = (const int*)d_in[1];
    const float* gcn_w1   = (const float*)d_in[2];
    const float* gcn_b1   = (const float*)d_in[3];
    const float* gcn_w2   = (const float*)d_in[4];
    const float* gcn_b2   = (const float*)d_in[5];
    const float* sage_wl1 = (const float*)d_in[6];
    const float* sage_bl1 = (const float*)d_in[7];
    const float* sage_wr1 = (const float*)d_in[8];
    const float* sage_wl2 = (const float*)d_in[9];
    const float* sage_bl2 = (const float*)d_in[10];
    const float* sage_wr2 = (const float*)d_in[11];
    const float* gcn_ln_g = (const float*)d_in[12];
    const float* gcn_ln_b = (const float*)d_in[13];
    const float* sage_ln_g = (const float*)d_in[14];
    const float* sage_ln_b = (const float*)d_in[15];
    const float* proj_w   = (const float*)d_in[16];
    const float* proj_b   = (const float*)d_in[17];
    float* out = (float*)d_out;

    const int N = in_sizes[0] / 64;
    const int E = in_sizes[1] / 2;
    const int B = (N + SCAN_CHUNK - 1) / SCAN_CHUNK;

    char* w = (char*)d_ws;
    size_t off = 0;
    auto alloc = [&](size_t bytes) -> void* {
        void* p = w + off;
        off = (off + bytes + 255) & ~(size_t)255;
        return p;
    };
    int*   cnt       = (int*)alloc((size_t)N * 4);
    int*   offs      = (int*)alloc((size_t)N * 4);
    int*   cursor    = (int*)alloc((size_t)N * 4);
    float* dinv      = (float*)alloc((size_t)N * 4);
    int*   blockSums = (int*)alloc((size_t)(B + 1) * 4);
    int*   csr       = (int*)alloc((size_t)E * 4);
    float* buf1      = (float*)alloc((size_t)N * 128 * 4);  // (g | s1)
    (void)ws_size; (void)n_in; (void)out_size;

    hipMemsetAsync(cnt, 0, (size_t)N * 4, stream);
    hipMemsetAsync(cursor, 0, (size_t)N * 4, stream);

    int e4Blocks = ((E + 3) / 4 + 255) / 256;
    k_count<<<e4Blocks, 256, 0, stream>>>(ei, E, cnt);
    k_scan_reduce<<<B, 256, 0, stream>>>(cnt, N, blockSums);
    k_scan_spine<<<1, 64, 0, stream>>>(blockSums, B);
    k_scan_write<<<B, 256, 0, stream>>>(cnt, N, blockSums, offs, dinv);
    k_fill<<<e4Blocks, 256, 0, stream>>>(ei, E, offs, cursor, csr);

    int nodeBlocks = (N + 63) / 64;  // 16 waves x 4 nodes per block
    k_layer1_fused<<<nodeBlocks, 1024, 0, stream>>>(x, csr, offs, cnt, dinv,
                                                    gcn_w1, gcn_b1, sage_wl1, sage_bl1,
                                                    sage_wr1, buf1, N);
    k_layer2_fused<<<nodeBlocks, 1024, 0, stream>>>(buf1, csr, offs, cnt, dinv,
                                                    gcn_w2, gcn_b2, sage_wl2, sage_bl2,
                                                    sage_wr2, gcn_ln_g, gcn_ln_b,
                                                    sage_ln_g, sage_ln_b, proj_w, proj_b,
                                                    out, N);
}

// Round 5
// 4487.731 us; speedup vs baseline: 1.0080x; 1.0080x over previous
//
#include <hip/hip_runtime.h>

// N=100000 nodes, E=1250000 edges, all dims 64. fp32 end-to-end.
// R5: R4's 4-nodes-per-wave spilled (VGPR capped 64 by default 8-waves/EU
// target -> 8.4GB scratch traffic, 2840us). LDS already caps occupancy at
// 4 waves/EU, so declare __launch_bounds__(1024, 4) -> 128-VGPR budget,
// no spills, keep the 4x weight-read amortization.

#define SCAN_CHUNK 2048

__global__ void k_count(const int* __restrict__ ei, int E, int* __restrict__ cnt) {
    int i = blockIdx.x * blockDim.x + threadIdx.x;
    int e = i * 4;
    if (e + 4 <= E) {
        int4 d = *(const int4*)&ei[E + e];
        atomicAdd(&cnt[d.x], 1); atomicAdd(&cnt[d.y], 1);
        atomicAdd(&cnt[d.z], 1); atomicAdd(&cnt[d.w], 1);
    } else {
        for (int j = e; j < E; ++j) atomicAdd(&cnt[ei[E + j]], 1);
    }
}

__global__ void k_scan_reduce(const int* __restrict__ cnt, int N, int* __restrict__ blockSums) {
    __shared__ int lds[256];
    int base = blockIdx.x * SCAN_CHUNK;
    int t = threadIdx.x;
    int s = 0;
    for (int j = 0; j < 8; ++j) {
        int idx = base + t * 8 + j;
        if (idx < N) s += cnt[idx];
    }
    lds[t] = s;
    __syncthreads();
    for (int d = 128; d > 0; d >>= 1) {
        if (t < d) lds[t] += lds[t + d];
        __syncthreads();
    }
    if (t == 0) blockSums[blockIdx.x] = lds[0];
}

__global__ void k_scan_spine(int* __restrict__ blockSums, int B) {
    if (threadIdx.x == 0 && blockIdx.x == 0) {
        int run = 0;
        for (int b = 0; b < B; ++b) { int v = blockSums[b]; blockSums[b] = run; run += v; }
    }
}

__global__ void k_scan_write(const int* __restrict__ cnt, int N,
                             const int* __restrict__ blockSums,
                             int* __restrict__ offs, float* __restrict__ dinv) {
    __shared__ int lds[256];
    int base = blockIdx.x * SCAN_CHUNK;
    int t = threadIdx.x;
    int v[8];
    int s = 0;
    for (int j = 0; j < 8; ++j) {
        int idx = base + t * 8 + j;
        v[j] = (idx < N) ? cnt[idx] : 0;
        s += v[j];
    }
    lds[t] = s;
    __syncthreads();
    for (int d = 1; d < 256; d <<= 1) {
        int x = (t >= d) ? lds[t - d] : 0;
        __syncthreads();
        lds[t] += x;
        __syncthreads();
    }
    int excl = (t == 0) ? 0 : lds[t - 1];
    int run = blockSums[blockIdx.x] + excl;
    for (int j = 0; j < 8; ++j) {
        int idx = base + t * 8 + j;
        if (idx < N) {
            offs[idx] = run;
            run += v[j];
            dinv[idx] = rsqrtf((float)v[j] + 1.0f);
        }
    }
}

__global__ void k_fill(const int* __restrict__ ei, int E, const int* __restrict__ offs,
                       int* __restrict__ cursor, int* __restrict__ csr) {
    int i = blockIdx.x * blockDim.x + threadIdx.x;
    int e = i * 4;
    if (e + 4 <= E) {
        int4 s = *(const int4*)&ei[e];
        int4 d = *(const int4*)&ei[E + e];
        csr[offs[d.x] + atomicAdd(&cursor[d.x], 1)] = s.x;
        csr[offs[d.y] + atomicAdd(&cursor[d.y], 1)] = s.y;
        csr[offs[d.z] + atomicAdd(&cursor[d.z], 1)] = s.z;
        csr[offs[d.w] + atomicAdd(&cursor[d.w], 1)] = s.w;
    } else {
        for (int j = e; j < E; ++j) {
            int s = ei[j], d = ei[E + j];
            csr[offs[d] + atomicAdd(&cursor[d], 1)] = s;
        }
    }
}

__device__ __forceinline__ void xor_reduce8(float4& a, float4& b) {
    a.x += __shfl_xor(a.x, 16, 64); a.y += __shfl_xor(a.y, 16, 64);
    a.z += __shfl_xor(a.z, 16, 64); a.w += __shfl_xor(a.w, 16, 64);
    b.x += __shfl_xor(b.x, 16, 64); b.y += __shfl_xor(b.y, 16, 64);
    b.z += __shfl_xor(b.z, 16, 64); b.w += __shfl_xor(b.w, 16, 64);
    a.x += __shfl_xor(a.x, 32, 64); a.y += __shfl_xor(a.y, 32, 64);
    a.z += __shfl_xor(a.z, 32, 64); a.w += __shfl_xor(a.w, 32, 64);
    b.x += __shfl_xor(b.x, 32, 64); b.y += __shfl_xor(b.y, 32, 64);
    b.z += __shfl_xor(b.z, 32, 64); b.w += __shfl_xor(b.w, 32, 64);
}

// Layer 1: each wave gathers 4 nodes (x, GCN-weighted + SAGE-mean), stages
// (gin|sin|xv) per node into its LDS slot, then fused GEMMs with weights
// read once per 4 nodes. buf1[node] = (relu(g) | relu(s1)).
__launch_bounds__(1024, 4)
__global__ void k_layer1_fused(const float* __restrict__ x, const int* __restrict__ csr,
                               const int* __restrict__ offs, const int* __restrict__ cnt,
                               const float* __restrict__ dinv,
                               const float* __restrict__ W1, const float* __restrict__ b1,
                               const float* __restrict__ Wl1, const float* __restrict__ bl1,
                               const float* __restrict__ Wr1,
                               float* __restrict__ buf1, int N) {
    __shared__ float sW1[64 * 68], sWl[64 * 68], sWr[64 * 68];  // 52.2 KB
    __shared__ float sS[16 * 4 * 192];                          // 48 KB
    int t = threadIdx.x;
    for (int i = t; i < 4096; i += 1024) {
        int k = i >> 6, o = i & 63;
        sW1[o * 68 + k] = W1[i];
        sWl[o * 68 + k] = Wl1[i];
        sWr[o * 68 + k] = Wr1[i];
    }
    __syncthreads();

    int lane = t & 63;
    int wave = t >> 6;
    int c = lane & 15, grp = lane >> 4;
    int wbase = wave * 768;
    int base_node = (blockIdx.x * 16 + wave) * 4;

    for (int j = 0; j < 4; ++j) {
        int node = base_node + j;
        if (node >= N) break;
        int st = offs[node];
        int cn = cnt[node];
        float di = dinv[node];

        float4 aA = {0.f, 0.f, 0.f, 0.f}, aB = {0.f, 0.f, 0.f, 0.f};
        for (int e = 0; e < cn; e += 8) {
            int i0 = e + grp, i1 = e + 4 + grp;
            float m0 = (i0 < cn) ? 1.f : 0.f;
            float m1 = (i1 < cn) ? 1.f : 0.f;
            int s0 = csr[st + (i0 < cn ? i0 : cn - 1)];
            int s1 = csr[st + (i1 < cn ? i1 : cn - 1)];
            float w0 = m0 * dinv[s0];
            float w1 = m1 * dinv[s1];
            float4 v0 = *(const float4*)&x[(size_t)s0 * 64 + 4 * c];
            float4 v1 = *(const float4*)&x[(size_t)s1 * 64 + 4 * c];
            aA.x += w0 * v0.x + w1 * v1.x; aA.y += w0 * v0.y + w1 * v1.y;
            aA.z += w0 * v0.z + w1 * v1.z; aA.w += w0 * v0.w + w1 * v1.w;
            aB.x += m0 * v0.x + m1 * v1.x; aB.y += m0 * v0.y + m1 * v1.y;
            aB.z += m0 * v0.z + m1 * v1.z; aB.w += m0 * v0.w + m1 * v1.w;
        }
        xor_reduce8(aA, aB);

        float4 selfq = *(const float4*)&x[(size_t)node * 64 + 4 * c];
        float4 val;
        if (grp == 0) {
            float d2 = di * di;
            val.x = di * aA.x + d2 * selfq.x; val.y = di * aA.y + d2 * selfq.y;
            val.z = di * aA.z + d2 * selfq.z; val.w = di * aA.w + d2 * selfq.w;
        } else if (grp == 1) {
            float rn = 1.0f / fmaxf((float)cn, 1.0f);
            val.x = aB.x * rn; val.y = aB.y * rn; val.z = aB.z * rn; val.w = aB.w * rn;
        } else {
            val = selfq;  // xv (grp==2); grp==3 masked off
        }
        if (grp < 3) *(float4*)&sS[wbase + j * 192 + grp * 64 + 4 * c] = val;
    }
    // wave-local LDS dependency only; compiler emits lgkmcnt waits. No barrier.

    float bg = b1[lane], bs = bl1[lane];
    float accG[4] = {bg, bg, bg, bg};
    float accS[4] = {bs, bs, bs, bs};
    #pragma unroll
    for (int kq = 0; kq < 16; ++kq) {
        float4 w1 = *(const float4*)&sW1[lane * 68 + 4 * kq];
        float4 wl = *(const float4*)&sWl[lane * 68 + 4 * kq];
        float4 wr = *(const float4*)&sWr[lane * 68 + 4 * kq];
        #pragma unroll
        for (int j = 0; j < 4; ++j) {
            const float* slot = &sS[wbase + j * 192];
            float4 ia = *(const float4*)&slot[4 * kq];
            float4 ib = *(const float4*)&slot[64 + 4 * kq];
            float4 ic = *(const float4*)&slot[128 + 4 * kq];
            accG[j] += ia.x * w1.x + ia.y * w1.y + ia.z * w1.z + ia.w * w1.w;
            accS[j] += ib.x * wl.x + ib.y * wl.y + ib.z * wl.z + ib.w * wl.w
                     + ic.x * wr.x + ic.y * wr.y + ic.z * wr.z + ic.w * wr.w;
        }
    }
    #pragma unroll
    for (int j = 0; j < 4; ++j) {
        int node = base_node + j;
        if (node < N) {
            buf1[(size_t)node * 128 + lane]      = fmaxf(accG[j], 0.f);
            buf1[(size_t)node * 128 + 64 + lane] = fmaxf(accS[j], 0.f);
        }
    }
}

// Layer 2: gather(g,s1) for 4 nodes/wave -> GEMMs -> LN -> concat-proj -> out.
__launch_bounds__(1024, 4)
__global__ void k_layer2_fused(const float* __restrict__ gs, const int* __restrict__ csr,
                               const int* __restrict__ offs, const int* __restrict__ cnt,
                               const float* __restrict__ dinv,
                               const float* __restrict__ W2, const float* __restrict__ b2,
                               const float* __restrict__ Wl2, const float* __restrict__ bl2,
                               const float* __restrict__ Wr2,
                               const float* __restrict__ lngG, const float* __restrict__ lnbG,
                               const float* __restrict__ lngS, const float* __restrict__ lnbS,
                               const float* __restrict__ Pw, const float* __restrict__ Pb,
                               float* __restrict__ out, int N) {
    __shared__ float sW2[64 * 68], sWl[64 * 68], sWr[64 * 68];  // 52.2 KB
    __shared__ float sPt[64 * 132];                             // 33.8 KB
    __shared__ float sS[16 * 4 * 192];                          // 48 KB
    int t = threadIdx.x;
    for (int i = t; i < 4096; i += 1024) {
        int k = i >> 6, o = i & 63;
        sW2[o * 68 + k] = W2[i];
        sWl[o * 68 + k] = Wl2[i];
        sWr[o * 68 + k] = Wr2[i];
    }
    for (int i = t; i < 8192; i += 1024) {
        int k = i >> 6, o = i & 63;
        sPt[o * 132 + k] = Pw[i];
    }
    __syncthreads();

    int lane = t & 63;
    int wave = t >> 6;
    int c = lane & 15, grp = lane >> 4;
    int wbase = wave * 768;
    int base_node = (blockIdx.x * 16 + wave) * 4;

    for (int j = 0; j < 4; ++j) {
        int node = base_node + j;
        if (node >= N) break;
        int st = offs[node];
        int cn = cnt[node];
        float di = dinv[node];

        float4 aC = {0.f, 0.f, 0.f, 0.f}, aD = {0.f, 0.f, 0.f, 0.f};
        for (int e = 0; e < cn; e += 8) {
            int i0 = e + grp, i1 = e + 4 + grp;
            float m0 = (i0 < cn) ? 1.f : 0.f;
            float m1 = (i1 < cn) ? 1.f : 0.f;
            int s0 = csr[st + (i0 < cn ? i0 : cn - 1)];
            int s1 = csr[st + (i1 < cn ? i1 : cn - 1)];
            float w0 = m0 * dinv[s0];
            float w1 = m1 * dinv[s1];
            const float* p0 = gs + (size_t)s0 * 128 + 4 * c;
            const float* p1 = gs + (size_t)s1 * 128 + 4 * c;
            float4 g0 = *(const float4*)p0;
            float4 g1 = *(const float4*)p1;
            float4 t0 = *(const float4*)(p0 + 64);
            float4 t1 = *(const float4*)(p1 + 64);
            aC.x += w0 * g0.x + w1 * g1.x; aC.y += w0 * g0.y + w1 * g1.y;
            aC.z += w0 * g0.z + w1 * g1.z; aC.w += w0 * g0.w + w1 * g1.w;
            aD.x += m0 * t0.x + m1 * t1.x; aD.y += m0 * t0.y + m1 * t1.y;
            aD.z += m0 * t0.z + m1 * t1.z; aD.w += m0 * t0.w + m1 * t1.w;
        }
        xor_reduce8(aC, aD);

        float4 selfq = *(const float4*)&gs[(size_t)node * 128 + (grp == 2 ? 64 : 0) + 4 * c];
        float4 val;
        if (grp == 0) {
            float d2 = di * di;
            val.x = di * aC.x + d2 * selfq.x; val.y = di * aC.y + d2 * selfq.y;
            val.z = di * aC.z + d2 * selfq.z; val.w = di * aC.w + d2 * selfq.w;
        } else if (grp == 1) {
            float rn = 1.0f / fmaxf((float)cn, 1.0f);
            val.x = aD.x * rn; val.y = aD.y * rn; val.z = aD.z * rn; val.w = aD.w * rn;
        } else {
            val = selfq;  // sv (grp==2); grp==3 masked off
        }
        if (grp < 3) *(float4*)&sS[wbase + j * 192 + grp * 64 + 4 * c] = val;
    }

    float accG[4], accS[4];
    #pragma unroll
    for (int j = 0; j < 4; ++j) { accG[j] = 0.f; accS[j] = 0.f; }
    #pragma unroll
    for (int kq = 0; kq < 16; ++kq) {
        float4 w2 = *(const float4*)&sW2[lane * 68 + 4 * kq];
        float4 wl = *(const float4*)&sWl[lane * 68 + 4 * kq];
        float4 wr = *(const float4*)&sWr[lane * 68 + 4 * kq];
        #pragma unroll
        for (int j = 0; j < 4; ++j) {
            const float* slot = &sS[wbase + j * 192];
            float4 ia = *(const float4*)&slot[4 * kq];
            float4 ib = *(const float4*)&slot[64 + 4 * kq];
            float4 ic = *(const float4*)&slot[128 + 4 * kq];
            accG[j] += ia.x * w2.x + ia.y * w2.y + ia.z * w2.z + ia.w * w2.w;
            accS[j] += ib.x * wl.x + ib.y * wl.y + ib.z * wl.z + ib.w * wl.w
                     + ic.x * wr.x + ic.y * wr.y + ic.z * wr.z + ic.w * wr.w;
        }
    }

    float bg = b2[lane], bs = bl2[lane];
    float gG = lngG[lane], bG = lnbG[lane], gS = lngS[lane], bS = lnbS[lane];

    #pragma unroll
    for (int j = 0; j < 4; ++j) {
        float aGv = accG[j] + bg;
        float aSv = accS[j] + bs;
        float sG = aGv, qG = aGv * aGv, sSs = aSv, qS = aSv * aSv;
        #pragma unroll
        for (int m = 1; m < 64; m <<= 1) {
            sG += __shfl_xor(sG, m, 64);
            qG += __shfl_xor(qG, m, 64);
            sSs += __shfl_xor(sSs, m, 64);
            qS += __shfl_xor(qS, m, 64);
        }
        float muG = sG * (1.0f / 64.0f);
        float varG = fmaxf(qG * (1.0f / 64.0f) - muG * muG, 0.0f);
        float muS = sSs * (1.0f / 64.0f);
        float varS = fmaxf(qS * (1.0f / 64.0f) - muS * muS, 0.0f);
        float gln = (aGv - muG) * rsqrtf(varG + 1e-5f) * gG + bG;
        float sln = (aSv - muS) * rsqrtf(varS + 1e-5f) * gS + bS;
        sS[wbase + j * 192 + lane] = gln;
        sS[wbase + j * 192 + 64 + lane] = sln;
    }

    float accO[4];
    float pb = Pb[lane];
    #pragma unroll
    for (int j = 0; j < 4; ++j) accO[j] = pb;
    #pragma unroll
    for (int kq = 0; kq < 16; ++kq) {
        float4 p0 = *(const float4*)&sPt[lane * 132 + 4 * kq];
        float4 p1 = *(const float4*)&sPt[lane * 132 + 64 + 4 * kq];
        #pragma unroll
        for (int j = 0; j < 4; ++j) {
            const float* slot = &sS[wbase + j * 192];
            float4 u0 = *(const float4*)&slot[4 * kq];
            float4 u1 = *(const float4*)&slot[64 + 4 * kq];
            accO[j] += u0.x * p0.x + u0.y * p0.y + u0.z * p0.z + u0.w * p0.w
                     + u1.x * p1.x + u1.y * p1.y + u1.z * p1.z + u1.w * p1.w;
        }
    }
    #pragma unroll
    for (int j = 0; j < 4; ++j) {
        int node = base_node + j;
        if (node < N) out[(size_t)node * 64 + lane] = accO[j];
    }
}

extern "C" void kernel_launch(void* const* d_in, const int* in_sizes, int n_in,
                              void* d_out, int out_size, void* d_ws, size_t ws_size,
                              hipStream_t stream) {
    const float* x        = (const float*)d_in[0];
    const int*   ei       = (const int*)d_in[1];
    const float* gcn_w1   = (const float*)d_in[2];
    const float* gcn_b1   = (const float*)d_in[3];
    const float* gcn_w2   = (const float*)d_in[4];
    const float* gcn_b2   = (const float*)d_in[5];
    const float* sage_wl1 = (const float*)d_in[6];
    const float* sage_bl1 = (const float*)d_in[7];
    const float* sage_wr1 = (const float*)d_in[8];
    const float* sage_wl2 = (const float*)d_in[9];
    const float* sage_bl2 = (const float*)d_in[10];
    const float* sage_wr2 = (const float*)d_in[11];
    const float* gcn_ln_g = (const float*)d_in[12];
    const float* gcn_ln_b = (const float*)d_in[13];
    const float* sage_ln_g = (const float*)d_in[14];
    const float* sage_ln_b = (const float*)d_in[15];
    const float* proj_w   = (const float*)d_in[16];
    const float* proj_b   = (const float*)d_in[17];
    float* out = (float*)d_out;

    const int N = in_sizes[0] / 64;
    const int E = in_sizes[1] / 2;
    const int B = (N + SCAN_CHUNK - 1) / SCAN_CHUNK;

    char* w = (char*)d_ws;
    size_t off = 0;
    auto alloc = [&](size_t bytes) -> void* {
        void* p = w + off;
        off = (off + bytes + 255) & ~(size_t)255;
        return p;
    };
    int*   cnt       = (int*)alloc((size_t)N * 4);
    int*   offs      = (int*)alloc((size_t)N * 4);
    int*   cursor    = (int*)alloc((size_t)N * 4);
    float* dinv      = (float*)alloc((size_t)N * 4);
    int*   blockSums = (int*)alloc((size_t)(B + 1) * 4);
    int*   csr       = (int*)alloc((size_t)E * 4);
    float* buf1      = (float*)alloc((size_t)N * 128 * 4);  // (g | s1)
    (void)ws_size; (void)n_in; (void)out_size;

    hipMemsetAsync(cnt, 0, (size_t)N * 4, stream);
    hipMemsetAsync(cursor, 0, (size_t)N * 4, stream);

    int e4Blocks = ((E + 3) / 4 + 255) / 256;
    k_count<<<e4Blocks, 256, 0, stream>>>(ei, E, cnt);
    k_scan_reduce<<<B, 256, 0, stream>>>(cnt, N, blockSums);
    k_scan_spine<<<1, 64, 0, stream>>>(blockSums, B);
    k_scan_write<<<B, 256, 0, stream>>>(cnt, N, blockSums, offs, dinv);
    k_fill<<<e4Blocks, 256, 0, stream>>>(ei, E, offs, cursor, csr);

    int nodeBlocks = (N + 63) / 64;  // 16 waves x 4 nodes per block
    k_layer1_fused<<<nodeBlocks, 1024, 0, stream>>>(x, csr, offs, cnt, dinv,
                                                    gcn_w1, gcn_b1, sage_wl1, sage_bl1,
                                                    sage_wr1, buf1, N);
    k_layer2_fused<<<nodeBlocks, 1024, 0, stream>>>(buf1, csr, offs, cnt, dinv,
                                                    gcn_w2, gcn_b2, sage_wl2, sage_bl2,
                                                    sage_wr2, gcn_ln_g, gcn_ln_b,
                                                    sage_ln_g, sage_ln_b, proj_w, proj_b,
                                                    out, N);
}

// Round 6
// 631.741 us; speedup vs baseline: 7.1603x; 7.1037x over previous
//
#include <hip/hip_runtime.h>

// N=100000 nodes, E=1250000 edges, all dims 64. fp32 end-to-end.
// R6: R4/R5 spilled because full unroll of kq(16) x nodes(4) GEMM loops
// ballooned the live set (~240 pending b128 LDS loads) past any VGPR budget
// -> 8.4GB scratch traffic. Fix: keep kq loops ROLLED (#pragma unroll 1);
// live set per iteration ~50 VGPR. Weight reads stay amortized 4x.

#define SCAN_CHUNK 2048

__global__ void k_count(const int* __restrict__ ei, int E, int* __restrict__ cnt) {
    int i = blockIdx.x * blockDim.x + threadIdx.x;
    int e = i * 4;
    if (e + 4 <= E) {
        int4 d = *(const int4*)&ei[E + e];
        atomicAdd(&cnt[d.x], 1); atomicAdd(&cnt[d.y], 1);
        atomicAdd(&cnt[d.z], 1); atomicAdd(&cnt[d.w], 1);
    } else {
        for (int j = e; j < E; ++j) atomicAdd(&cnt[ei[E + j]], 1);
    }
}

__global__ void k_scan_reduce(const int* __restrict__ cnt, int N, int* __restrict__ blockSums) {
    __shared__ int lds[256];
    int base = blockIdx.x * SCAN_CHUNK;
    int t = threadIdx.x;
    int s = 0;
    for (int j = 0; j < 8; ++j) {
        int idx = base + t * 8 + j;
        if (idx < N) s += cnt[idx];
    }
    lds[t] = s;
    __syncthreads();
    for (int d = 128; d > 0; d >>= 1) {
        if (t < d) lds[t] += lds[t + d];
        __syncthreads();
    }
    if (t == 0) blockSums[blockIdx.x] = lds[0];
}

__global__ void k_scan_spine(int* __restrict__ blockSums, int B) {
    if (threadIdx.x == 0 && blockIdx.x == 0) {
        int run = 0;
        for (int b = 0; b < B; ++b) { int v = blockSums[b]; blockSums[b] = run; run += v; }
    }
}

__global__ void k_scan_write(const int* __restrict__ cnt, int N,
                             const int* __restrict__ blockSums,
                             int* __restrict__ offs, float* __restrict__ dinv) {
    __shared__ int lds[256];
    int base = blockIdx.x * SCAN_CHUNK;
    int t = threadIdx.x;
    int v[8];
    int s = 0;
    for (int j = 0; j < 8; ++j) {
        int idx = base + t * 8 + j;
        v[j] = (idx < N) ? cnt[idx] : 0;
        s += v[j];
    }
    lds[t] = s;
    __syncthreads();
    for (int d = 1; d < 256; d <<= 1) {
        int x = (t >= d) ? lds[t - d] : 0;
        __syncthreads();
        lds[t] += x;
        __syncthreads();
    }
    int excl = (t == 0) ? 0 : lds[t - 1];
    int run = blockSums[blockIdx.x] + excl;
    for (int j = 0; j < 8; ++j) {
        int idx = base + t * 8 + j;
        if (idx < N) {
            offs[idx] = run;
            run += v[j];
            dinv[idx] = rsqrtf((float)v[j] + 1.0f);
        }
    }
}

__global__ void k_fill(const int* __restrict__ ei, int E, const int* __restrict__ offs,
                       int* __restrict__ cursor, int* __restrict__ csr) {
    int i = blockIdx.x * blockDim.x + threadIdx.x;
    int e = i * 4;
    if (e + 4 <= E) {
        int4 s = *(const int4*)&ei[e];
        int4 d = *(const int4*)&ei[E + e];
        csr[offs[d.x] + atomicAdd(&cursor[d.x], 1)] = s.x;
        csr[offs[d.y] + atomicAdd(&cursor[d.y], 1)] = s.y;
        csr[offs[d.z] + atomicAdd(&cursor[d.z], 1)] = s.z;
        csr[offs[d.w] + atomicAdd(&cursor[d.w], 1)] = s.w;
    } else {
        for (int j = e; j < E; ++j) {
            int s = ei[j], d = ei[E + j];
            csr[offs[d] + atomicAdd(&cursor[d], 1)] = s;
        }
    }
}

__device__ __forceinline__ void xor_reduce8(float4& a, float4& b) {
    a.x += __shfl_xor(a.x, 16, 64); a.y += __shfl_xor(a.y, 16, 64);
    a.z += __shfl_xor(a.z, 16, 64); a.w += __shfl_xor(a.w, 16, 64);
    b.x += __shfl_xor(b.x, 16, 64); b.y += __shfl_xor(b.y, 16, 64);
    b.z += __shfl_xor(b.z, 16, 64); b.w += __shfl_xor(b.w, 16, 64);
    a.x += __shfl_xor(a.x, 32, 64); a.y += __shfl_xor(a.y, 32, 64);
    a.z += __shfl_xor(a.z, 32, 64); a.w += __shfl_xor(a.w, 32, 64);
    b.x += __shfl_xor(b.x, 32, 64); b.y += __shfl_xor(b.y, 32, 64);
    b.z += __shfl_xor(b.z, 32, 64); b.w += __shfl_xor(b.w, 32, 64);
}

// Layer 1: each wave gathers 4 nodes (x, GCN-weighted + SAGE-mean), stages
// (gin|sin|xv) per node into its LDS slot, then fused GEMMs with weights
// read once per 4 nodes. buf1[node] = (relu(g) | relu(s1)).
__launch_bounds__(1024, 4)
__global__ void k_layer1_fused(const float* __restrict__ x, const int* __restrict__ csr,
                               const int* __restrict__ offs, const int* __restrict__ cnt,
                               const float* __restrict__ dinv,
                               const float* __restrict__ W1, const float* __restrict__ b1,
                               const float* __restrict__ Wl1, const float* __restrict__ bl1,
                               const float* __restrict__ Wr1,
                               float* __restrict__ buf1, int N) {
    __shared__ float sW1[64 * 68], sWl[64 * 68], sWr[64 * 68];  // 52.2 KB
    __shared__ float sS[16 * 4 * 192];                          // 48 KB
    int t = threadIdx.x;
    for (int i = t; i < 4096; i += 1024) {
        int k = i >> 6, o = i & 63;
        sW1[o * 68 + k] = W1[i];
        sWl[o * 68 + k] = Wl1[i];
        sWr[o * 68 + k] = Wr1[i];
    }
    __syncthreads();

    int lane = t & 63;
    int wave = t >> 6;
    int c = lane & 15, grp = lane >> 4;
    int wbase = wave * 768;
    int base_node = (blockIdx.x * 16 + wave) * 4;

    #pragma unroll 1
    for (int j = 0; j < 4; ++j) {
        int node = base_node + j;
        if (node >= N) break;
        int st = offs[node];
        int cn = cnt[node];
        float di = dinv[node];

        float4 aA = {0.f, 0.f, 0.f, 0.f}, aB = {0.f, 0.f, 0.f, 0.f};
        #pragma unroll 1
        for (int e = 0; e < cn; e += 8) {
            int i0 = e + grp, i1 = e + 4 + grp;
            float m0 = (i0 < cn) ? 1.f : 0.f;
            float m1 = (i1 < cn) ? 1.f : 0.f;
            int s0 = csr[st + (i0 < cn ? i0 : cn - 1)];
            int s1 = csr[st + (i1 < cn ? i1 : cn - 1)];
            float w0 = m0 * dinv[s0];
            float w1 = m1 * dinv[s1];
            float4 v0 = *(const float4*)&x[(size_t)s0 * 64 + 4 * c];
            float4 v1 = *(const float4*)&x[(size_t)s1 * 64 + 4 * c];
            aA.x += w0 * v0.x + w1 * v1.x; aA.y += w0 * v0.y + w1 * v1.y;
            aA.z += w0 * v0.z + w1 * v1.z; aA.w += w0 * v0.w + w1 * v1.w;
            aB.x += m0 * v0.x + m1 * v1.x; aB.y += m0 * v0.y + m1 * v1.y;
            aB.z += m0 * v0.z + m1 * v1.z; aB.w += m0 * v0.w + m1 * v1.w;
        }
        xor_reduce8(aA, aB);

        float4 selfq = *(const float4*)&x[(size_t)node * 64 + 4 * c];
        float4 val;
        if (grp == 0) {
            float d2 = di * di;
            val.x = di * aA.x + d2 * selfq.x; val.y = di * aA.y + d2 * selfq.y;
            val.z = di * aA.z + d2 * selfq.z; val.w = di * aA.w + d2 * selfq.w;
        } else if (grp == 1) {
            float rn = 1.0f / fmaxf((float)cn, 1.0f);
            val.x = aB.x * rn; val.y = aB.y * rn; val.z = aB.z * rn; val.w = aB.w * rn;
        } else {
            val = selfq;  // xv (grp==2); grp==3 masked off
        }
        if (grp < 3) *(float4*)&sS[wbase + j * 192 + grp * 64 + 4 * c] = val;
    }
    // wave-local LDS dependency only; compiler emits lgkmcnt waits. No barrier.

    float bg = b1[lane], bs = bl1[lane];
    float accG[4] = {bg, bg, bg, bg};
    float accS[4] = {bs, bs, bs, bs};
    #pragma unroll 1
    for (int kq = 0; kq < 16; ++kq) {
        float4 w1 = *(const float4*)&sW1[lane * 68 + 4 * kq];
        float4 wl = *(const float4*)&sWl[lane * 68 + 4 * kq];
        float4 wr = *(const float4*)&sWr[lane * 68 + 4 * kq];
        #pragma unroll
        for (int j = 0; j < 4; ++j) {
            const float* slot = &sS[wbase + j * 192];
            float4 ia = *(const float4*)&slot[4 * kq];
            float4 ib = *(const float4*)&slot[64 + 4 * kq];
            float4 ic = *(const float4*)&slot[128 + 4 * kq];
            accG[j] += ia.x * w1.x + ia.y * w1.y + ia.z * w1.z + ia.w * w1.w;
            accS[j] += ib.x * wl.x + ib.y * wl.y + ib.z * wl.z + ib.w * wl.w
                     + ic.x * wr.x + ic.y * wr.y + ic.z * wr.z + ic.w * wr.w;
        }
    }
    #pragma unroll
    for (int j = 0; j < 4; ++j) {
        int node = base_node + j;
        if (node < N) {
            buf1[(size_t)node * 128 + lane]      = fmaxf(accG[j], 0.f);
            buf1[(size_t)node * 128 + 64 + lane] = fmaxf(accS[j], 0.f);
        }
    }
}

// Layer 2: gather(g,s1) for 4 nodes/wave -> GEMMs -> LN -> concat-proj -> out.
__launch_bounds__(1024, 4)
__global__ void k_layer2_fused(const float* __restrict__ gs, const int* __restrict__ csr,
                               const int* __restrict__ offs, const int* __restrict__ cnt,
                               const float* __restrict__ dinv,
                               const float* __restrict__ W2, const float* __restrict__ b2,
                               const float* __restrict__ Wl2, const float* __restrict__ bl2,
                               const float* __restrict__ Wr2,
                               const float* __restrict__ lngG, const float* __restrict__ lnbG,
                               const float* __restrict__ lngS, const float* __restrict__ lnbS,
                               const float* __restrict__ Pw, const float* __restrict__ Pb,
                               float* __restrict__ out, int N) {
    __shared__ float sW2[64 * 68], sWl[64 * 68], sWr[64 * 68];  // 52.2 KB
    __shared__ float sPt[64 * 132];                             // 33.8 KB
    __shared__ float sS[16 * 4 * 192];                          // 48 KB
    int t = threadIdx.x;
    for (int i = t; i < 4096; i += 1024) {
        int k = i >> 6, o = i & 63;
        sW2[o * 68 + k] = W2[i];
        sWl[o * 68 + k] = Wl2[i];
        sWr[o * 68 + k] = Wr2[i];
    }
    for (int i = t; i < 8192; i += 1024) {
        int k = i >> 6, o = i & 63;
        sPt[o * 132 + k] = Pw[i];
    }
    __syncthreads();

    int lane = t & 63;
    int wave = t >> 6;
    int c = lane & 15, grp = lane >> 4;
    int wbase = wave * 768;
    int base_node = (blockIdx.x * 16 + wave) * 4;

    #pragma unroll 1
    for (int j = 0; j < 4; ++j) {
        int node = base_node + j;
        if (node >= N) break;
        int st = offs[node];
        int cn = cnt[node];
        float di = dinv[node];

        float4 aC = {0.f, 0.f, 0.f, 0.f}, aD = {0.f, 0.f, 0.f, 0.f};
        #pragma unroll 1
        for (int e = 0; e < cn; e += 8) {
            int i0 = e + grp, i1 = e + 4 + grp;
            float m0 = (i0 < cn) ? 1.f : 0.f;
            float m1 = (i1 < cn) ? 1.f : 0.f;
            int s0 = csr[st + (i0 < cn ? i0 : cn - 1)];
            int s1 = csr[st + (i1 < cn ? i1 : cn - 1)];
            float w0 = m0 * dinv[s0];
            float w1 = m1 * dinv[s1];
            const float* p0 = gs + (size_t)s0 * 128 + 4 * c;
            const float* p1 = gs + (size_t)s1 * 128 + 4 * c;
            float4 g0 = *(const float4*)p0;
            float4 g1 = *(const float4*)p1;
            float4 t0 = *(const float4*)(p0 + 64);
            float4 t1 = *(const float4*)(p1 + 64);
            aC.x += w0 * g0.x + w1 * g1.x; aC.y += w0 * g0.y + w1 * g1.y;
            aC.z += w0 * g0.z + w1 * g1.z; aC.w += w0 * g0.w + w1 * g1.w;
            aD.x += m0 * t0.x + m1 * t1.x; aD.y += m0 * t0.y + m1 * t1.y;
            aD.z += m0 * t0.z + m1 * t1.z; aD.w += m0 * t0.w + m1 * t1.w;
        }
        xor_reduce8(aC, aD);

        float4 selfq = *(const float4*)&gs[(size_t)node * 128 + (grp == 2 ? 64 : 0) + 4 * c];
        float4 val;
        if (grp == 0) {
            float d2 = di * di;
            val.x = di * aC.x + d2 * selfq.x; val.y = di * aC.y + d2 * selfq.y;
            val.z = di * aC.z + d2 * selfq.z; val.w = di * aC.w + d2 * selfq.w;
        } else if (grp == 1) {
            float rn = 1.0f / fmaxf((float)cn, 1.0f);
            val.x = aD.x * rn; val.y = aD.y * rn; val.z = aD.z * rn; val.w = aD.w * rn;
        } else {
            val = selfq;  // sv (grp==2); grp==3 masked off
        }
        if (grp < 3) *(float4*)&sS[wbase + j * 192 + grp * 64 + 4 * c] = val;
    }

    float accG[4], accS[4];
    #pragma unroll
    for (int j = 0; j < 4; ++j) { accG[j] = 0.f; accS[j] = 0.f; }
    #pragma unroll 1
    for (int kq = 0; kq < 16; ++kq) {
        float4 w2 = *(const float4*)&sW2[lane * 68 + 4 * kq];
        float4 wl = *(const float4*)&sWl[lane * 68 + 4 * kq];
        float4 wr = *(const float4*)&sWr[lane * 68 + 4 * kq];
        #pragma unroll
        for (int j = 0; j < 4; ++j) {
            const float* slot = &sS[wbase + j * 192];
            float4 ia = *(const float4*)&slot[4 * kq];
            float4 ib = *(const float4*)&slot[64 + 4 * kq];
            float4 ic = *(const float4*)&slot[128 + 4 * kq];
            accG[j] += ia.x * w2.x + ia.y * w2.y + ia.z * w2.z + ia.w * w2.w;
            accS[j] += ib.x * wl.x + ib.y * wl.y + ib.z * wl.z + ib.w * wl.w
                     + ic.x * wr.x + ic.y * wr.y + ic.z * wr.z + ic.w * wr.w;
        }
    }

    float bg = b2[lane], bs = bl2[lane];
    float gG = lngG[lane], bG = lnbG[lane], gS = lngS[lane], bS = lnbS[lane];

    #pragma unroll 1
    for (int j = 0; j < 4; ++j) {
        float aGv = accG[j] + bg;
        float aSv = accS[j] + bs;
        float sG = aGv, qG = aGv * aGv, sSs = aSv, qS = aSv * aSv;
        #pragma unroll
        for (int m = 1; m < 64; m <<= 1) {
            sG += __shfl_xor(sG, m, 64);
            qG += __shfl_xor(qG, m, 64);
            sSs += __shfl_xor(sSs, m, 64);
            qS += __shfl_xor(qS, m, 64);
        }
        float muG = sG * (1.0f / 64.0f);
        float varG = fmaxf(qG * (1.0f / 64.0f) - muG * muG, 0.0f);
        float muS = sSs * (1.0f / 64.0f);
        float varS = fmaxf(qS * (1.0f / 64.0f) - muS * muS, 0.0f);
        float gln = (aGv - muG) * rsqrtf(varG + 1e-5f) * gG + bG;
        float sln = (aSv - muS) * rsqrtf(varS + 1e-5f) * gS + bS;
        sS[wbase + j * 192 + lane] = gln;
        sS[wbase + j * 192 + 64 + lane] = sln;
    }

    float accO[4];
    float pb = Pb[lane];
    #pragma unroll
    for (int j = 0; j < 4; ++j) accO[j] = pb;
    #pragma unroll 1
    for (int kq = 0; kq < 16; ++kq) {
        float4 p0 = *(const float4*)&sPt[lane * 132 + 4 * kq];
        float4 p1 = *(const float4*)&sPt[lane * 132 + 64 + 4 * kq];
        #pragma unroll
        for (int j = 0; j < 4; ++j) {
            const float* slot = &sS[wbase + j * 192];
            float4 u0 = *(const float4*)&slot[4 * kq];
            float4 u1 = *(const float4*)&slot[64 + 4 * kq];
            accO[j] += u0.x * p0.x + u0.y * p0.y + u0.z * p0.z + u0.w * p0.w
                     + u1.x * p1.x + u1.y * p1.y + u1.z * p1.z + u1.w * p1.w;
        }
    }
    #pragma unroll
    for (int j = 0; j < 4; ++j) {
        int node = base_node + j;
        if (node < N) out[(size_t)node * 64 + lane] = accO[j];
    }
}

extern "C" void kernel_launch(void* const* d_in, const int* in_sizes, int n_in,
                              void* d_out, int out_size, void* d_ws, size_t ws_size,
                              hipStream_t stream) {
    const float* x        = (const float*)d_in[0];
    const int*   ei       = (const int*)d_in[1];
    const float* gcn_w1   = (const float*)d_in[2];
    const float* gcn_b1   = (const float*)d_in[3];
    const float* gcn_w2   = (const float*)d_in[4];
    const float* gcn_b2   = (const float*)d_in[5];
    const float* sage_wl1 = (const float*)d_in[6];
    const float* sage_bl1 = (const float*)d_in[7];
    const float* sage_wr1 = (const float*)d_in[8];
    const float* sage_wl2 = (const float*)d_in[9];
    const float* sage_bl2 = (const float*)d_in[10];
    const float* sage_wr2 = (const float*)d_in[11];
    const float* gcn_ln_g = (const float*)d_in[12];
    const float* gcn_ln_b = (const float*)d_in[13];
    const float* sage_ln_g = (const float*)d_in[14];
    const float* sage_ln_b = (const float*)d_in[15];
    const float* proj_w   = (const float*)d_in[16];
    const float* proj_b   = (const float*)d_in[17];
    float* out = (float*)d_out;

    const int N = in_sizes[0] / 64;
    const int E = in_sizes[1] / 2;
    const int B = (N + SCAN_CHUNK - 1) / SCAN_CHUNK;

    char* w = (char*)d_ws;
    size_t off = 0;
    auto alloc = [&](size_t bytes) -> void* {
        void* p = w + off;
        off = (off + bytes + 255) & ~(size_t)255;
        return p;
    };
    int*   cnt       = (int*)alloc((size_t)N * 4);
    int*   offs      = (int*)alloc((size_t)N * 4);
    int*   cursor    = (int*)alloc((size_t)N * 4);
    float* dinv      = (float*)alloc((size_t)N * 4);
    int*   blockSums = (int*)alloc((size_t)(B + 1) * 4);
    int*   csr       = (int*)alloc((size_t)E * 4);
    float* buf1      = (float*)alloc((size_t)N * 128 * 4);  // (g | s1)
    (void)ws_size; (void)n_in; (void)out_size;

    hipMemsetAsync(cnt, 0, (size_t)N * 4, stream);
    hipMemsetAsync(cursor, 0, (size_t)N * 4, stream);

    int e4Blocks = ((E + 3) / 4 + 255) / 256;
    k_count<<<e4Blocks, 256, 0, stream>>>(ei, E, cnt);
    k_scan_reduce<<<B, 256, 0, stream>>>(cnt, N, blockSums);
    k_scan_spine<<<1, 64, 0, stream>>>(blockSums, B);
    k_scan_write<<<B, 256, 0, stream>>>(cnt, N, blockSums, offs, dinv);
    k_fill<<<e4Blocks, 256, 0, stream>>>(ei, E, offs, cursor, csr);

    int nodeBlocks = (N + 63) / 64;  // 16 waves x 4 nodes per block
    k_layer1_fused<<<nodeBlocks, 1024, 0, stream>>>(x, csr, offs, cnt, dinv,
                                                    gcn_w1, gcn_b1, sage_wl1, sage_bl1,
                                                    sage_wr1, buf1, N);
    k_layer2_fused<<<nodeBlocks, 1024, 0, stream>>>(buf1, csr, offs, cnt, dinv,
                                                    gcn_w2, gcn_b2, sage_wl2, sage_bl2,
                                                    sage_wr2, gcn_ln_g, gcn_ln_b,
                                                    sage_ln_g, sage_ln_b, proj_w, proj_b,
                                                    out, N);
}

// Round 7
// 546.970 us; speedup vs baseline: 8.2700x; 1.1550x over previous
//
#include <hip/hip_runtime.h>

// N=100000 nodes, E=1250000 edges, all dims 64.
// R7: layer kernels are LDS-pipe-bound; ~65% of DS ops are per-node input
// broadcasts that cannot be amortized in the VALU scheme. MFMA moves the
// K-broadcast/reduce into the matrix pipe. This round: layer1 -> gather
// (bf16 agg) + MFMA GEMM; buf1 becomes bf16 (halves layer2 gather bytes);
// layer2 keeps the proven R6 structure with bf16 row reads.

#define SCAN_CHUNK 2048

typedef __attribute__((ext_vector_type(8))) short short8;   // 8 bf16 = 4 VGPRs
typedef __attribute__((ext_vector_type(4))) float floatx4;  // MFMA C/D

__device__ __forceinline__ unsigned short f2bf(float f) {
    unsigned int u = __float_as_uint(f);
    unsigned int r = u + 0x7FFFu + ((u >> 16) & 1u);  // round-to-nearest-even
    return (unsigned short)(r >> 16);
}
__device__ __forceinline__ float bf2f(unsigned short h) {
    return __uint_as_float(((unsigned int)h) << 16);
}

__global__ void k_count(const int* __restrict__ ei, int E, int* __restrict__ cnt) {
    int i = blockIdx.x * blockDim.x + threadIdx.x;
    int e = i * 4;
    if (e + 4 <= E) {
        int4 d = *(const int4*)&ei[E + e];
        atomicAdd(&cnt[d.x], 1); atomicAdd(&cnt[d.y], 1);
        atomicAdd(&cnt[d.z], 1); atomicAdd(&cnt[d.w], 1);
    } else {
        for (int j = e; j < E; ++j) atomicAdd(&cnt[ei[E + j]], 1);
    }
}

__global__ void k_scan_reduce(const int* __restrict__ cnt, int N, int* __restrict__ blockSums) {
    __shared__ int lds[256];
    int base = blockIdx.x * SCAN_CHUNK;
    int t = threadIdx.x;
    int s = 0;
    for (int j = 0; j < 8; ++j) {
        int idx = base + t * 8 + j;
        if (idx < N) s += cnt[idx];
    }
    lds[t] = s;
    __syncthreads();
    for (int d = 128; d > 0; d >>= 1) {
        if (t < d) lds[t] += lds[t + d];
        __syncthreads();
    }
    if (t == 0) blockSums[blockIdx.x] = lds[0];
}

__global__ void k_scan_spine(int* __restrict__ blockSums, int B) {
    if (threadIdx.x == 0 && blockIdx.x == 0) {
        int run = 0;
        for (int b = 0; b < B; ++b) { int v = blockSums[b]; blockSums[b] = run; run += v; }
    }
}

__global__ void k_scan_write(const int* __restrict__ cnt, int N,
                             const int* __restrict__ blockSums,
                             int* __restrict__ offs, float* __restrict__ dinv) {
    __shared__ int lds[256];
    int base = blockIdx.x * SCAN_CHUNK;
    int t = threadIdx.x;
    int v[8];
    int s = 0;
    for (int j = 0; j < 8; ++j) {
        int idx = base + t * 8 + j;
        v[j] = (idx < N) ? cnt[idx] : 0;
        s += v[j];
    }
    lds[t] = s;
    __syncthreads();
    for (int d = 1; d < 256; d <<= 1) {
        int x = (t >= d) ? lds[t - d] : 0;
        __syncthreads();
        lds[t] += x;
        __syncthreads();
    }
    int excl = (t == 0) ? 0 : lds[t - 1];
    int run = blockSums[blockIdx.x] + excl;
    for (int j = 0; j < 8; ++j) {
        int idx = base + t * 8 + j;
        if (idx < N) {
            offs[idx] = run;
            run += v[j];
            dinv[idx] = rsqrtf((float)v[j] + 1.0f);
        }
    }
}

__global__ void k_fill(const int* __restrict__ ei, int E, const int* __restrict__ offs,
                       int* __restrict__ cursor, int* __restrict__ csr) {
    int i = blockIdx.x * blockDim.x + threadIdx.x;
    int e = i * 4;
    if (e + 4 <= E) {
        int4 s = *(const int4*)&ei[e];
        int4 d = *(const int4*)&ei[E + e];
        csr[offs[d.x] + atomicAdd(&cursor[d.x], 1)] = s.x;
        csr[offs[d.y] + atomicAdd(&cursor[d.y], 1)] = s.y;
        csr[offs[d.z] + atomicAdd(&cursor[d.z], 1)] = s.z;
        csr[offs[d.w] + atomicAdd(&cursor[d.w], 1)] = s.w;
    } else {
        for (int j = e; j < E; ++j) {
            int s = ei[j], d = ei[E + j];
            csr[offs[d] + atomicAdd(&cursor[d], 1)] = s;
        }
    }
}

__device__ __forceinline__ void xor_reduce8(float4& a, float4& b) {
    a.x += __shfl_xor(a.x, 16, 64); a.y += __shfl_xor(a.y, 16, 64);
    a.z += __shfl_xor(a.z, 16, 64); a.w += __shfl_xor(a.w, 16, 64);
    b.x += __shfl_xor(b.x, 16, 64); b.y += __shfl_xor(b.y, 16, 64);
    b.z += __shfl_xor(b.z, 16, 64); b.w += __shfl_xor(b.w, 16, 64);
    a.x += __shfl_xor(a.x, 32, 64); a.y += __shfl_xor(a.y, 32, 64);
    a.z += __shfl_xor(a.z, 32, 64); a.w += __shfl_xor(a.w, 32, 64);
    b.x += __shfl_xor(b.x, 32, 64); b.y += __shfl_xor(b.y, 32, 64);
    b.z += __shfl_xor(b.z, 32, 64); b.w += __shfl_xor(b.w, 32, 64);
}

// Gather for layer1: one wave per node. agg[node] = [gin(64) | sin(64)] bf16.
__global__ void k_gather1(const float* __restrict__ x, const int* __restrict__ csr,
                          const int* __restrict__ offs, const int* __restrict__ cnt,
                          const float* __restrict__ dinv,
                          unsigned short* __restrict__ agg, int N) {
    int lane = threadIdx.x & 63;
    int wave = threadIdx.x >> 6;
    int node = blockIdx.x * 4 + wave;
    if (node >= N) return;
    int c = lane & 15, grp = lane >> 4;

    int st = offs[node];
    int cn = cnt[node];
    float di = dinv[node];

    float4 aA = {0.f, 0.f, 0.f, 0.f}, aB = {0.f, 0.f, 0.f, 0.f};
    for (int e = 0; e < cn; e += 8) {
        int i0 = e + grp, i1 = e + 4 + grp;
        float m0 = (i0 < cn) ? 1.f : 0.f;
        float m1 = (i1 < cn) ? 1.f : 0.f;
        int s0 = csr[st + (i0 < cn ? i0 : cn - 1)];
        int s1 = csr[st + (i1 < cn ? i1 : cn - 1)];
        float w0 = m0 * dinv[s0];
        float w1 = m1 * dinv[s1];
        float4 v0 = *(const float4*)&x[(size_t)s0 * 64 + 4 * c];
        float4 v1 = *(const float4*)&x[(size_t)s1 * 64 + 4 * c];
        aA.x += w0 * v0.x + w1 * v1.x; aA.y += w0 * v0.y + w1 * v1.y;
        aA.z += w0 * v0.z + w1 * v1.z; aA.w += w0 * v0.w + w1 * v1.w;
        aB.x += m0 * v0.x + m1 * v1.x; aB.y += m0 * v0.y + m1 * v1.y;
        aB.z += m0 * v0.z + m1 * v1.z; aB.w += m0 * v0.w + m1 * v1.w;
    }
    xor_reduce8(aA, aB);

    if (grp == 0) {
        float4 sq = *(const float4*)&x[(size_t)node * 64 + 4 * c];
        float d2 = di * di;
        ushort4 o;
        o.x = f2bf(di * aA.x + d2 * sq.x); o.y = f2bf(di * aA.y + d2 * sq.y);
        o.z = f2bf(di * aA.z + d2 * sq.z); o.w = f2bf(di * aA.w + d2 * sq.w);
        *(ushort4*)&agg[(size_t)node * 128 + 4 * c] = o;
    } else if (grp == 1) {
        float rn = 1.0f / fmaxf((float)cn, 1.0f);
        ushort4 o;
        o.x = f2bf(aB.x * rn); o.y = f2bf(aB.y * rn);
        o.z = f2bf(aB.z * rn); o.w = f2bf(aB.w * rn);
        *(ushort4*)&agg[(size_t)node * 128 + 64 + 4 * c] = o;
    }
}

// Layer-1 GEMMs via MFMA 16x16x32 bf16. Block 512 = 8 waves, 16 nodes/wave.
// B-frags pre-swizzled fragment-major in LDS: frag f = kstep*4+ntile holds
// B[k=32*kstep+quad*8+j][n=16*ntile+(lane&15)] at [f*512 + lane*8 + j].
// A-frags: A[m=lane&15][k=quad*8+j] read directly from agg/x rows.
// D: row m = quad*4+reg, col n = lane&15 (per measured C/D layout).
__launch_bounds__(512, 1)
__global__ void k_gemm1(const unsigned short* __restrict__ agg, const float* __restrict__ x,
                        const float* __restrict__ W1, const float* __restrict__ b1,
                        const float* __restrict__ Wl1, const float* __restrict__ bl1,
                        const float* __restrict__ Wr1,
                        unsigned short* __restrict__ buf1, int N) {
    alignas(16) __shared__ unsigned short sW[3][4096];  // 24 KB, 3 x (8 frags x 512)
    int t = threadIdx.x;
    for (int i = t; i < 1536; i += 512) {
        int m = i >> 9;
        int rem = i & 511;
        int f = rem >> 6;
        int L = rem & 63;
        int kb = (f >> 2) * 32 + (L >> 4) * 8;
        int o = (f & 3) * 16 + (L & 15);
        const float* Wsrc = (m == 0) ? W1 : (m == 1) ? Wl1 : Wr1;
        unsigned short* dst = &sW[m][f * 512 + L * 8];
        #pragma unroll
        for (int j = 0; j < 8; ++j) dst[j] = f2bf(Wsrc[(kb + j) * 64 + o]);
    }
    __syncthreads();

    int lane = t & 63;
    int wave = t >> 6;
    int quad = lane >> 4;
    int n16 = lane & 15;
    int base = blockIdx.x * 128 + wave * 16;
    if (base >= N) return;

    int nm = base + n16;
    if (nm >= N) nm = N - 1;
    const unsigned short* ar = agg + (size_t)nm * 128;

    // ---- GCN branch: gin @ W1 ----
    {
        short8 a0 = *(const short8*)(ar + quad * 8);
        short8 a1 = *(const short8*)(ar + 32 + quad * 8);
        floatx4 g0 = {0.f, 0.f, 0.f, 0.f}, g1 = g0, g2 = g0, g3 = g0;
        g0 = __builtin_amdgcn_mfma_f32_16x16x32_bf16(a0, *(const short8*)&sW[0][(0 * 4 + 0) * 512 + lane * 8], g0, 0, 0, 0);
        g0 = __builtin_amdgcn_mfma_f32_16x16x32_bf16(a1, *(const short8*)&sW[0][(1 * 4 + 0) * 512 + lane * 8], g0, 0, 0, 0);
        g1 = __builtin_amdgcn_mfma_f32_16x16x32_bf16(a0, *(const short8*)&sW[0][(0 * 4 + 1) * 512 + lane * 8], g1, 0, 0, 0);
        g1 = __builtin_amdgcn_mfma_f32_16x16x32_bf16(a1, *(const short8*)&sW[0][(1 * 4 + 1) * 512 + lane * 8], g1, 0, 0, 0);
        g2 = __builtin_amdgcn_mfma_f32_16x16x32_bf16(a0, *(const short8*)&sW[0][(0 * 4 + 2) * 512 + lane * 8], g2, 0, 0, 0);
        g2 = __builtin_amdgcn_mfma_f32_16x16x32_bf16(a1, *(const short8*)&sW[0][(1 * 4 + 2) * 512 + lane * 8], g2, 0, 0, 0);
        g3 = __builtin_amdgcn_mfma_f32_16x16x32_bf16(a0, *(const short8*)&sW[0][(0 * 4 + 3) * 512 + lane * 8], g3, 0, 0, 0);
        g3 = __builtin_amdgcn_mfma_f32_16x16x32_bf16(a1, *(const short8*)&sW[0][(1 * 4 + 3) * 512 + lane * 8], g3, 0, 0, 0);
        floatx4 gt[4] = {g0, g1, g2, g3};
        #pragma unroll
        for (int nt = 0; nt < 4; ++nt) {
            float bg = b1[nt * 16 + n16];
            #pragma unroll
            for (int r = 0; r < 4; ++r) {
                int node = base + quad * 4 + r;
                if (node < N)
                    buf1[(size_t)node * 128 + nt * 16 + n16] = f2bf(fmaxf(gt[nt][r] + bg, 0.f));
            }
        }
    }

    // ---- SAGE branch: sin @ Wl1 + x @ Wr1 ----
    {
        short8 a0 = *(const short8*)(ar + 64 + quad * 8);
        short8 a1 = *(const short8*)(ar + 96 + quad * 8);
        // xv frags from fp32 x
        float4 xq0 = *(const float4*)&x[(size_t)nm * 64 + quad * 8];
        float4 xq1 = *(const float4*)&x[(size_t)nm * 64 + quad * 8 + 4];
        float4 xq2 = *(const float4*)&x[(size_t)nm * 64 + 32 + quad * 8];
        float4 xq3 = *(const float4*)&x[(size_t)nm * 64 + 32 + quad * 8 + 4];
        short8 ax0, ax1;
        ax0[0] = (short)f2bf(xq0.x); ax0[1] = (short)f2bf(xq0.y);
        ax0[2] = (short)f2bf(xq0.z); ax0[3] = (short)f2bf(xq0.w);
        ax0[4] = (short)f2bf(xq1.x); ax0[5] = (short)f2bf(xq1.y);
        ax0[6] = (short)f2bf(xq1.z); ax0[7] = (short)f2bf(xq1.w);
        ax1[0] = (short)f2bf(xq2.x); ax1[1] = (short)f2bf(xq2.y);
        ax1[2] = (short)f2bf(xq2.z); ax1[3] = (short)f2bf(xq2.w);
        ax1[4] = (short)f2bf(xq3.x); ax1[5] = (short)f2bf(xq3.y);
        ax1[6] = (short)f2bf(xq3.z); ax1[7] = (short)f2bf(xq3.w);

        floatx4 s0 = {0.f, 0.f, 0.f, 0.f}, s1 = s0, s2 = s0, s3 = s0;
        s0 = __builtin_amdgcn_mfma_f32_16x16x32_bf16(a0, *(const short8*)&sW[1][(0 * 4 + 0) * 512 + lane * 8], s0, 0, 0, 0);
        s0 = __builtin_amdgcn_mfma_f32_16x16x32_bf16(a1, *(const short8*)&sW[1][(1 * 4 + 0) * 512 + lane * 8], s0, 0, 0, 0);
        s0 = __builtin_amdgcn_mfma_f32_16x16x32_bf16(ax0, *(const short8*)&sW[2][(0 * 4 + 0) * 512 + lane * 8], s0, 0, 0, 0);
        s0 = __builtin_amdgcn_mfma_f32_16x16x32_bf16(ax1, *(const short8*)&sW[2][(1 * 4 + 0) * 512 + lane * 8], s0, 0, 0, 0);
        s1 = __builtin_amdgcn_mfma_f32_16x16x32_bf16(a0, *(const short8*)&sW[1][(0 * 4 + 1) * 512 + lane * 8], s1, 0, 0, 0);
        s1 = __builtin_amdgcn_mfma_f32_16x16x32_bf16(a1, *(const short8*)&sW[1][(1 * 4 + 1) * 512 + lane * 8], s1, 0, 0, 0);
        s1 = __builtin_amdgcn_mfma_f32_16x16x32_bf16(ax0, *(const short8*)&sW[2][(0 * 4 + 1) * 512 + lane * 8], s1, 0, 0, 0);
        s1 = __builtin_amdgcn_mfma_f32_16x16x32_bf16(ax1, *(const short8*)&sW[2][(1 * 4 + 1) * 512 + lane * 8], s1, 0, 0, 0);
        s2 = __builtin_amdgcn_mfma_f32_16x16x32_bf16(a0, *(const short8*)&sW[1][(0 * 4 + 2) * 512 + lane * 8], s2, 0, 0, 0);
        s2 = __builtin_amdgcn_mfma_f32_16x16x32_bf16(a1, *(const short8*)&sW[1][(1 * 4 + 2) * 512 + lane * 8], s2, 0, 0, 0);
        s2 = __builtin_amdgcn_mfma_f32_16x16x32_bf16(ax0, *(const short8*)&sW[2][(0 * 4 + 2) * 512 + lane * 8], s2, 0, 0, 0);
        s2 = __builtin_amdgcn_mfma_f32_16x16x32_bf16(ax1, *(const short8*)&sW[2][(1 * 4 + 2) * 512 + lane * 8], s2, 0, 0, 0);
        s3 = __builtin_amdgcn_mfma_f32_16x16x32_bf16(a0, *(const short8*)&sW[1][(0 * 4 + 3) * 512 + lane * 8], s3, 0, 0, 0);
        s3 = __builtin_amdgcn_mfma_f32_16x16x32_bf16(a1, *(const short8*)&sW[1][(1 * 4 + 3) * 512 + lane * 8], s3, 0, 0, 0);
        s3 = __builtin_amdgcn_mfma_f32_16x16x32_bf16(ax0, *(const short8*)&sW[2][(0 * 4 + 3) * 512 + lane * 8], s3, 0, 0, 0);
        s3 = __builtin_amdgcn_mfma_f32_16x16x32_bf16(ax1, *(const short8*)&sW[2][(1 * 4 + 3) * 512 + lane * 8], s3, 0, 0, 0);
        floatx4 stl[4] = {s0, s1, s2, s3};
        #pragma unroll
        for (int nt = 0; nt < 4; ++nt) {
            float bs = bl1[nt * 16 + n16];
            #pragma unroll
            for (int r = 0; r < 4; ++r) {
                int node = base + quad * 4 + r;
                if (node < N)
                    buf1[(size_t)node * 128 + 64 + nt * 16 + n16] = f2bf(fmaxf(stl[nt][r] + bs, 0.f));
            }
        }
    }
}

// Layer 2 (R6 structure): gather(g,s1 bf16) 4 nodes/wave -> fp32 GEMMs ->
// LN -> concat-proj -> out.
__launch_bounds__(1024, 4)
__global__ void k_layer2_fused(const unsigned short* __restrict__ gs, const int* __restrict__ csr,
                               const int* __restrict__ offs, const int* __restrict__ cnt,
                               const float* __restrict__ dinv,
                               const float* __restrict__ W2, const float* __restrict__ b2,
                               const float* __restrict__ Wl2, const float* __restrict__ bl2,
                               const float* __restrict__ Wr2,
                               const float* __restrict__ lngG, const float* __restrict__ lnbG,
                               const float* __restrict__ lngS, const float* __restrict__ lnbS,
                               const float* __restrict__ Pw, const float* __restrict__ Pb,
                               float* __restrict__ out, int N) {
    __shared__ float sW2[64 * 68], sWl[64 * 68], sWr[64 * 68];  // 52.2 KB
    __shared__ float sPt[64 * 132];                             // 33.8 KB
    __shared__ float sS[16 * 4 * 192];                          // 48 KB
    int t = threadIdx.x;
    for (int i = t; i < 4096; i += 1024) {
        int k = i >> 6, o = i & 63;
        sW2[o * 68 + k] = W2[i];
        sWl[o * 68 + k] = Wl2[i];
        sWr[o * 68 + k] = Wr2[i];
    }
    for (int i = t; i < 8192; i += 1024) {
        int k = i >> 6, o = i & 63;
        sPt[o * 132 + k] = Pw[i];
    }
    __syncthreads();

    int lane = t & 63;
    int wave = t >> 6;
    int c = lane & 15, grp = lane >> 4;
    int wbase = wave * 768;
    int base_node = (blockIdx.x * 16 + wave) * 4;

    #pragma unroll 1
    for (int j = 0; j < 4; ++j) {
        int node = base_node + j;
        if (node >= N) break;
        int st = offs[node];
        int cn = cnt[node];
        float di = dinv[node];

        float4 aC = {0.f, 0.f, 0.f, 0.f}, aD = {0.f, 0.f, 0.f, 0.f};
        #pragma unroll 1
        for (int e = 0; e < cn; e += 8) {
            int i0 = e + grp, i1 = e + 4 + grp;
            float m0 = (i0 < cn) ? 1.f : 0.f;
            float m1 = (i1 < cn) ? 1.f : 0.f;
            int s0 = csr[st + (i0 < cn ? i0 : cn - 1)];
            int s1 = csr[st + (i1 < cn ? i1 : cn - 1)];
            float w0 = m0 * dinv[s0];
            float w1 = m1 * dinv[s1];
            const unsigned short* p0 = gs + (size_t)s0 * 128 + 4 * c;
            const unsigned short* p1 = gs + (size_t)s1 * 128 + 4 * c;
            ushort4 g0u = *(const ushort4*)p0;
            ushort4 g1u = *(const ushort4*)p1;
            ushort4 t0u = *(const ushort4*)(p0 + 64);
            ushort4 t1u = *(const ushort4*)(p1 + 64);
            aC.x += w0 * bf2f(g0u.x) + w1 * bf2f(g1u.x);
            aC.y += w0 * bf2f(g0u.y) + w1 * bf2f(g1u.y);
            aC.z += w0 * bf2f(g0u.z) + w1 * bf2f(g1u.z);
            aC.w += w0 * bf2f(g0u.w) + w1 * bf2f(g1u.w);
            aD.x += m0 * bf2f(t0u.x) + m1 * bf2f(t1u.x);
            aD.y += m0 * bf2f(t0u.y) + m1 * bf2f(t1u.y);
            aD.z += m0 * bf2f(t0u.z) + m1 * bf2f(t1u.z);
            aD.w += m0 * bf2f(t0u.w) + m1 * bf2f(t1u.w);
        }
        xor_reduce8(aC, aD);

        ushort4 su = *(const ushort4*)&gs[(size_t)node * 128 + (grp == 2 ? 64 : 0) + 4 * c];
        float4 selfq = {bf2f(su.x), bf2f(su.y), bf2f(su.z), bf2f(su.w)};
        float4 val;
        if (grp == 0) {
            float d2 = di * di;
            val.x = di * aC.x + d2 * selfq.x; val.y = di * aC.y + d2 * selfq.y;
            val.z = di * aC.z + d2 * selfq.z; val.w = di * aC.w + d2 * selfq.w;
        } else if (grp == 1) {
            float rn = 1.0f / fmaxf((float)cn, 1.0f);
            val.x = aD.x * rn; val.y = aD.y * rn; val.z = aD.z * rn; val.w = aD.w * rn;
        } else {
            val = selfq;  // sv (grp==2); grp==3 masked off
        }
        if (grp < 3) *(float4*)&sS[wbase + j * 192 + grp * 64 + 4 * c] = val;
    }

    float accG[4], accS[4];
    #pragma unroll
    for (int j = 0; j < 4; ++j) { accG[j] = 0.f; accS[j] = 0.f; }
    #pragma unroll 1
    for (int kq = 0; kq < 16; ++kq) {
        float4 w2 = *(const float4*)&sW2[lane * 68 + 4 * kq];
        float4 wl = *(const float4*)&sWl[lane * 68 + 4 * kq];
        float4 wr = *(const float4*)&sWr[lane * 68 + 4 * kq];
        #pragma unroll
        for (int j = 0; j < 4; ++j) {
            const float* slot = &sS[wbase + j * 192];
            float4 ia = *(const float4*)&slot[4 * kq];
            float4 ib = *(const float4*)&slot[64 + 4 * kq];
            float4 ic = *(const float4*)&slot[128 + 4 * kq];
            accG[j] += ia.x * w2.x + ia.y * w2.y + ia.z * w2.z + ia.w * w2.w;
            accS[j] += ib.x * wl.x + ib.y * wl.y + ib.z * wl.z + ib.w * wl.w
                     + ic.x * wr.x + ic.y * wr.y + ic.z * wr.z + ic.w * wr.w;
        }
    }

    float bg = b2[lane], bs = bl2[lane];
    float gG = lngG[lane], bG = lnbG[lane], gS = lngS[lane], bS = lnbS[lane];

    #pragma unroll 1
    for (int j = 0; j < 4; ++j) {
        float aGv = accG[j] + bg;
        float aSv = accS[j] + bs;
        float sG = aGv, qG = aGv * aGv, sSs = aSv, qS = aSv * aSv;
        #pragma unroll
        for (int m = 1; m < 64; m <<= 1) {
            sG += __shfl_xor(sG, m, 64);
            qG += __shfl_xor(qG, m, 64);
            sSs += __shfl_xor(sSs, m, 64);
            qS += __shfl_xor(qS, m, 64);
        }
        float muG = sG * (1.0f / 64.0f);
        float varG = fmaxf(qG * (1.0f / 64.0f) - muG * muG, 0.0f);
        float muS = sSs * (1.0f / 64.0f);
        float varS = fmaxf(qS * (1.0f / 64.0f) - muS * muS, 0.0f);
        float gln = (aGv - muG) * rsqrtf(varG + 1e-5f) * gG + bG;
        float sln = (aSv - muS) * rsqrtf(varS + 1e-5f) * gS + bS;
        sS[wbase + j * 192 + lane] = gln;
        sS[wbase + j * 192 + 64 + lane] = sln;
    }

    float accO[4];
    float pb = Pb[lane];
    #pragma unroll
    for (int j = 0; j < 4; ++j) accO[j] = pb;
    #pragma unroll 1
    for (int kq = 0; kq < 16; ++kq) {
        float4 p0 = *(const float4*)&sPt[lane * 132 + 4 * kq];
        float4 p1 = *(const float4*)&sPt[lane * 132 + 64 + 4 * kq];
        #pragma unroll
        for (int j = 0; j < 4; ++j) {
            const float* slot = &sS[wbase + j * 192];
            float4 u0 = *(const float4*)&slot[4 * kq];
            float4 u1 = *(const float4*)&slot[64 + 4 * kq];
            accO[j] += u0.x * p0.x + u0.y * p0.y + u0.z * p0.z + u0.w * p0.w
                     + u1.x * p1.x + u1.y * p1.y + u1.z * p1.z + u1.w * p1.w;
        }
    }
    #pragma unroll
    for (int j = 0; j < 4; ++j) {
        int node = base_node + j;
        if (node < N) out[(size_t)node * 64 + lane] = accO[j];
    }
}

extern "C" void kernel_launch(void* const* d_in, const int* in_sizes, int n_in,
                              void* d_out, int out_size, void* d_ws, size_t ws_size,
                              hipStream_t stream) {
    const float* x        = (const float*)d_in[0];
    const int*   ei       = (const int*)d_in[1];
    const float* gcn_w1   = (const float*)d_in[2];
    const float* gcn_b1   = (const float*)d_in[3];
    const float* gcn_w2   = (const float*)d_in[4];
    const float* gcn_b2   = (const float*)d_in[5];
    const float* sage_wl1 = (const float*)d_in[6];
    const float* sage_bl1 = (const float*)d_in[7];
    const float* sage_wr1 = (const float*)d_in[8];
    const float* sage_wl2 = (const float*)d_in[9];
    const float* sage_bl2 = (const float*)d_in[10];
    const float* sage_wr2 = (const float*)d_in[11];
    const float* gcn_ln_g = (const float*)d_in[12];
    const float* gcn_ln_b = (const float*)d_in[13];
    const float* sage_ln_g = (const float*)d_in[14];
    const float* sage_ln_b = (const float*)d_in[15];
    const float* proj_w   = (const float*)d_in[16];
    const float* proj_b   = (const float*)d_in[17];
    float* out = (float*)d_out;

    const int N = in_sizes[0] / 64;
    const int E = in_sizes[1] / 2;
    const int B = (N + SCAN_CHUNK - 1) / SCAN_CHUNK;

    char* w = (char*)d_ws;
    size_t off = 0;
    auto alloc = [&](size_t bytes) -> void* {
        void* p = w + off;
        off = (off + bytes + 255) & ~(size_t)255;
        return p;
    };
    int*            cnt       = (int*)alloc((size_t)N * 4);
    int*            offs      = (int*)alloc((size_t)N * 4);
    int*            cursor    = (int*)alloc((size_t)N * 4);
    float*          dinv      = (float*)alloc((size_t)N * 4);
    int*            blockSums = (int*)alloc((size_t)(B + 1) * 4);
    int*            csr       = (int*)alloc((size_t)E * 4);
    unsigned short* agg       = (unsigned short*)alloc((size_t)N * 128 * 2);  // gin|sin bf16
    unsigned short* buf1      = (unsigned short*)alloc((size_t)N * 128 * 2);  // g|s1 bf16
    (void)ws_size; (void)n_in; (void)out_size;

    hipMemsetAsync(cnt, 0, (size_t)N * 4, stream);
    hipMemsetAsync(cursor, 0, (size_t)N * 4, stream);

    int e4Blocks = ((E + 3) / 4 + 255) / 256;
    k_count<<<e4Blocks, 256, 0, stream>>>(ei, E, cnt);
    k_scan_reduce<<<B, 256, 0, stream>>>(cnt, N, blockSums);
    k_scan_spine<<<1, 64, 0, stream>>>(blockSums, B);
    k_scan_write<<<B, 256, 0, stream>>>(cnt, N, blockSums, offs, dinv);
    k_fill<<<e4Blocks, 256, 0, stream>>>(ei, E, offs, cursor, csr);

    k_gather1<<<(N + 3) / 4, 256, 0, stream>>>(x, csr, offs, cnt, dinv, agg, N);
    k_gemm1<<<(N + 127) / 128, 512, 0, stream>>>(agg, x, gcn_w1, gcn_b1,
                                                 sage_wl1, sage_bl1, sage_wr1, buf1, N);
    k_layer2_fused<<<(N + 63) / 64, 1024, 0, stream>>>(buf1, csr, offs, cnt, dinv,
                                                       gcn_w2, gcn_b2, sage_wl2, sage_bl2,
                                                       sage_wr2, gcn_ln_g, gcn_ln_b,
                                                       sage_ln_g, sage_ln_b, proj_w, proj_b,
                                                       out, N);
}

// Round 8
// 390.899 us; speedup vs baseline: 11.5719x; 1.3993x over previous
//
#include <hip/hip_runtime.h>

// N=100000 nodes, E=1250000 edges, all dims 64.
// R8: finish the MFMA migration. R7 proved layer1 gather+MFMA; layer2's
// remaining fp32 shuffle-GEMM+proj (~320 VALU fma/node, VALUBusy 55%) is now
// split the same way: k_gather2 (bf16 agg, reuses agg buffer) + k_gemm2
// (MFMA GEMMs -> LN in C-layout via 16-lane butterflies -> LDS transpose
// (stride 132: conflict-free writes, aligned b64 reads) -> MFMA proj).

#define SCAN_CHUNK 2048

typedef __attribute__((ext_vector_type(8))) short short8;   // 8 bf16 = 4 VGPRs
typedef __attribute__((ext_vector_type(4))) short short4v;  // 4 bf16 = 2 VGPRs
typedef __attribute__((ext_vector_type(4))) float floatx4;  // MFMA C/D

__device__ __forceinline__ unsigned short f2bf(float f) {
    unsigned int u = __float_as_uint(f);
    unsigned int r = u + 0x7FFFu + ((u >> 16) & 1u);  // round-to-nearest-even
    return (unsigned short)(r >> 16);
}
__device__ __forceinline__ float bf2f(unsigned short h) {
    return __uint_as_float(((unsigned int)h) << 16);
}

__global__ void k_count(const int* __restrict__ ei, int E, int* __restrict__ cnt) {
    int i = blockIdx.x * blockDim.x + threadIdx.x;
    int e = i * 4;
    if (e + 4 <= E) {
        int4 d = *(const int4*)&ei[E + e];
        atomicAdd(&cnt[d.x], 1); atomicAdd(&cnt[d.y], 1);
        atomicAdd(&cnt[d.z], 1); atomicAdd(&cnt[d.w], 1);
    } else {
        for (int j = e; j < E; ++j) atomicAdd(&cnt[ei[E + j]], 1);
    }
}

__global__ void k_scan_reduce(const int* __restrict__ cnt, int N, int* __restrict__ blockSums) {
    __shared__ int lds[256];
    int base = blockIdx.x * SCAN_CHUNK;
    int t = threadIdx.x;
    int s = 0;
    for (int j = 0; j < 8; ++j) {
        int idx = base + t * 8 + j;
        if (idx < N) s += cnt[idx];
    }
    lds[t] = s;
    __syncthreads();
    for (int d = 128; d > 0; d >>= 1) {
        if (t < d) lds[t] += lds[t + d];
        __syncthreads();
    }
    if (t == 0) blockSums[blockIdx.x] = lds[0];
}

__global__ void k_scan_spine(int* __restrict__ blockSums, int B) {
    if (threadIdx.x == 0 && blockIdx.x == 0) {
        int run = 0;
        for (int b = 0; b < B; ++b) { int v = blockSums[b]; blockSums[b] = run; run += v; }
    }
}

__global__ void k_scan_write(const int* __restrict__ cnt, int N,
                             const int* __restrict__ blockSums,
                             int* __restrict__ offs, float* __restrict__ dinv) {
    __shared__ int lds[256];
    int base = blockIdx.x * SCAN_CHUNK;
    int t = threadIdx.x;
    int v[8];
    int s = 0;
    for (int j = 0; j < 8; ++j) {
        int idx = base + t * 8 + j;
        v[j] = (idx < N) ? cnt[idx] : 0;
        s += v[j];
    }
    lds[t] = s;
    __syncthreads();
    for (int d = 1; d < 256; d <<= 1) {
        int x = (t >= d) ? lds[t - d] : 0;
        __syncthreads();
        lds[t] += x;
        __syncthreads();
    }
    int excl = (t == 0) ? 0 : lds[t - 1];
    int run = blockSums[blockIdx.x] + excl;
    for (int j = 0; j < 8; ++j) {
        int idx = base + t * 8 + j;
        if (idx < N) {
            offs[idx] = run;
            run += v[j];
            dinv[idx] = rsqrtf((float)v[j] + 1.0f);
        }
    }
}

__global__ void k_fill(const int* __restrict__ ei, int E, const int* __restrict__ offs,
                       int* __restrict__ cursor, int* __restrict__ csr) {
    int i = blockIdx.x * blockDim.x + threadIdx.x;
    int e = i * 4;
    if (e + 4 <= E) {
        int4 s = *(const int4*)&ei[e];
        int4 d = *(const int4*)&ei[E + e];
        csr[offs[d.x] + atomicAdd(&cursor[d.x], 1)] = s.x;
        csr[offs[d.y] + atomicAdd(&cursor[d.y], 1)] = s.y;
        csr[offs[d.z] + atomicAdd(&cursor[d.z], 1)] = s.z;
        csr[offs[d.w] + atomicAdd(&cursor[d.w], 1)] = s.w;
    } else {
        for (int j = e; j < E; ++j) {
            int s = ei[j], d = ei[E + j];
            csr[offs[d] + atomicAdd(&cursor[d], 1)] = s;
        }
    }
}

__device__ __forceinline__ void xor_reduce8(float4& a, float4& b) {
    a.x += __shfl_xor(a.x, 16, 64); a.y += __shfl_xor(a.y, 16, 64);
    a.z += __shfl_xor(a.z, 16, 64); a.w += __shfl_xor(a.w, 16, 64);
    b.x += __shfl_xor(b.x, 16, 64); b.y += __shfl_xor(b.y, 16, 64);
    b.z += __shfl_xor(b.z, 16, 64); b.w += __shfl_xor(b.w, 16, 64);
    a.x += __shfl_xor(a.x, 32, 64); a.y += __shfl_xor(a.y, 32, 64);
    a.z += __shfl_xor(a.z, 32, 64); a.w += __shfl_xor(a.w, 32, 64);
    b.x += __shfl_xor(b.x, 32, 64); b.y += __shfl_xor(b.y, 32, 64);
    b.z += __shfl_xor(b.z, 32, 64); b.w += __shfl_xor(b.w, 32, 64);
}

__device__ __forceinline__ float red16(float v) {
    v += __shfl_xor(v, 1, 64);
    v += __shfl_xor(v, 2, 64);
    v += __shfl_xor(v, 4, 64);
    v += __shfl_xor(v, 8, 64);
    return v;
}

// Gather for layer1: one wave per node. agg[node] = [gin(64) | sin(64)] bf16.
__global__ void k_gather1(const float* __restrict__ x, const int* __restrict__ csr,
                          const int* __restrict__ offs, const int* __restrict__ cnt,
                          const float* __restrict__ dinv,
                          unsigned short* __restrict__ agg, int N) {
    int lane = threadIdx.x & 63;
    int wave = threadIdx.x >> 6;
    int node = blockIdx.x * 4 + wave;
    if (node >= N) return;
    int c = lane & 15, grp = lane >> 4;

    int st = offs[node];
    int cn = cnt[node];
    float di = dinv[node];

    float4 aA = {0.f, 0.f, 0.f, 0.f}, aB = {0.f, 0.f, 0.f, 0.f};
    for (int e = 0; e < cn; e += 8) {
        int i0 = e + grp, i1 = e + 4 + grp;
        float m0 = (i0 < cn) ? 1.f : 0.f;
        float m1 = (i1 < cn) ? 1.f : 0.f;
        int s0 = csr[st + (i0 < cn ? i0 : cn - 1)];
        int s1 = csr[st + (i1 < cn ? i1 : cn - 1)];
        float w0 = m0 * dinv[s0];
        float w1 = m1 * dinv[s1];
        float4 v0 = *(const float4*)&x[(size_t)s0 * 64 + 4 * c];
        float4 v1 = *(const float4*)&x[(size_t)s1 * 64 + 4 * c];
        aA.x += w0 * v0.x + w1 * v1.x; aA.y += w0 * v0.y + w1 * v1.y;
        aA.z += w0 * v0.z + w1 * v1.z; aA.w += w0 * v0.w + w1 * v1.w;
        aB.x += m0 * v0.x + m1 * v1.x; aB.y += m0 * v0.y + m1 * v1.y;
        aB.z += m0 * v0.z + m1 * v1.z; aB.w += m0 * v0.w + m1 * v1.w;
    }
    xor_reduce8(aA, aB);

    if (grp == 0) {
        float4 sq = *(const float4*)&x[(size_t)node * 64 + 4 * c];
        float d2 = di * di;
        ushort4 o;
        o.x = f2bf(di * aA.x + d2 * sq.x); o.y = f2bf(di * aA.y + d2 * sq.y);
        o.z = f2bf(di * aA.z + d2 * sq.z); o.w = f2bf(di * aA.w + d2 * sq.w);
        *(ushort4*)&agg[(size_t)node * 128 + 4 * c] = o;
    } else if (grp == 1) {
        float rn = 1.0f / fmaxf((float)cn, 1.0f);
        ushort4 o;
        o.x = f2bf(aB.x * rn); o.y = f2bf(aB.y * rn);
        o.z = f2bf(aB.z * rn); o.w = f2bf(aB.w * rn);
        *(ushort4*)&agg[(size_t)node * 128 + 64 + 4 * c] = o;
    }
}

// Layer-1 GEMMs via MFMA 16x16x32 bf16 (proven in R7).
__launch_bounds__(512, 1)
__global__ void k_gemm1(const unsigned short* __restrict__ agg, const float* __restrict__ x,
                        const float* __restrict__ W1, const float* __restrict__ b1,
                        const float* __restrict__ Wl1, const float* __restrict__ bl1,
                        const float* __restrict__ Wr1,
                        unsigned short* __restrict__ buf1, int N) {
    alignas(16) __shared__ unsigned short sW[3][4096];
    int t = threadIdx.x;
    for (int i = t; i < 1536; i += 512) {
        int m = i >> 9;
        int rem = i & 511;
        int f = rem >> 6;
        int L = rem & 63;
        int kb = (f >> 2) * 32 + (L >> 4) * 8;
        int o = (f & 3) * 16 + (L & 15);
        const float* Wsrc = (m == 0) ? W1 : (m == 1) ? Wl1 : Wr1;
        unsigned short* dst = &sW[m][f * 512 + L * 8];
        #pragma unroll
        for (int j = 0; j < 8; ++j) dst[j] = f2bf(Wsrc[(kb + j) * 64 + o]);
    }
    __syncthreads();

    int lane = t & 63;
    int wave = t >> 6;
    int quad = lane >> 4;
    int n16 = lane & 15;
    int base = blockIdx.x * 128 + wave * 16;
    if (base >= N) return;

    int nm = base + n16;
    if (nm >= N) nm = N - 1;
    const unsigned short* ar = agg + (size_t)nm * 128;

    {
        short8 a0 = *(const short8*)(ar + quad * 8);
        short8 a1 = *(const short8*)(ar + 32 + quad * 8);
        floatx4 g0 = {0.f, 0.f, 0.f, 0.f}, g1 = g0, g2 = g0, g3 = g0;
        g0 = __builtin_amdgcn_mfma_f32_16x16x32_bf16(a0, *(const short8*)&sW[0][0 * 512 + lane * 8], g0, 0, 0, 0);
        g0 = __builtin_amdgcn_mfma_f32_16x16x32_bf16(a1, *(const short8*)&sW[0][4 * 512 + lane * 8], g0, 0, 0, 0);
        g1 = __builtin_amdgcn_mfma_f32_16x16x32_bf16(a0, *(const short8*)&sW[0][1 * 512 + lane * 8], g1, 0, 0, 0);
        g1 = __builtin_amdgcn_mfma_f32_16x16x32_bf16(a1, *(const short8*)&sW[0][5 * 512 + lane * 8], g1, 0, 0, 0);
        g2 = __builtin_amdgcn_mfma_f32_16x16x32_bf16(a0, *(const short8*)&sW[0][2 * 512 + lane * 8], g2, 0, 0, 0);
        g2 = __builtin_amdgcn_mfma_f32_16x16x32_bf16(a1, *(const short8*)&sW[0][6 * 512 + lane * 8], g2, 0, 0, 0);
        g3 = __builtin_amdgcn_mfma_f32_16x16x32_bf16(a0, *(const short8*)&sW[0][3 * 512 + lane * 8], g3, 0, 0, 0);
        g3 = __builtin_amdgcn_mfma_f32_16x16x32_bf16(a1, *(const short8*)&sW[0][7 * 512 + lane * 8], g3, 0, 0, 0);
        floatx4 gt[4] = {g0, g1, g2, g3};
        #pragma unroll
        for (int nt = 0; nt < 4; ++nt) {
            float bg = b1[nt * 16 + n16];
            #pragma unroll
            for (int r = 0; r < 4; ++r) {
                int node = base + quad * 4 + r;
                if (node < N)
                    buf1[(size_t)node * 128 + nt * 16 + n16] = f2bf(fmaxf(gt[nt][r] + bg, 0.f));
            }
        }
    }

    {
        short8 a0 = *(const short8*)(ar + 64 + quad * 8);
        short8 a1 = *(const short8*)(ar + 96 + quad * 8);
        float4 xq0 = *(const float4*)&x[(size_t)nm * 64 + quad * 8];
        float4 xq1 = *(const float4*)&x[(size_t)nm * 64 + quad * 8 + 4];
        float4 xq2 = *(const float4*)&x[(size_t)nm * 64 + 32 + quad * 8];
        float4 xq3 = *(const float4*)&x[(size_t)nm * 64 + 32 + quad * 8 + 4];
        short8 ax0, ax1;
        ax0[0] = (short)f2bf(xq0.x); ax0[1] = (short)f2bf(xq0.y);
        ax0[2] = (short)f2bf(xq0.z); ax0[3] = (short)f2bf(xq0.w);
        ax0[4] = (short)f2bf(xq1.x); ax0[5] = (short)f2bf(xq1.y);
        ax0[6] = (short)f2bf(xq1.z); ax0[7] = (short)f2bf(xq1.w);
        ax1[0] = (short)f2bf(xq2.x); ax1[1] = (short)f2bf(xq2.y);
        ax1[2] = (short)f2bf(xq2.z); ax1[3] = (short)f2bf(xq2.w);
        ax1[4] = (short)f2bf(xq3.x); ax1[5] = (short)f2bf(xq3.y);
        ax1[6] = (short)f2bf(xq3.z); ax1[7] = (short)f2bf(xq3.w);

        floatx4 s0 = {0.f, 0.f, 0.f, 0.f}, s1 = s0, s2 = s0, s3 = s0;
        s0 = __builtin_amdgcn_mfma_f32_16x16x32_bf16(a0, *(const short8*)&sW[1][0 * 512 + lane * 8], s0, 0, 0, 0);
        s0 = __builtin_amdgcn_mfma_f32_16x16x32_bf16(a1, *(const short8*)&sW[1][4 * 512 + lane * 8], s0, 0, 0, 0);
        s0 = __builtin_amdgcn_mfma_f32_16x16x32_bf16(ax0, *(const short8*)&sW[2][0 * 512 + lane * 8], s0, 0, 0, 0);
        s0 = __builtin_amdgcn_mfma_f32_16x16x32_bf16(ax1, *(const short8*)&sW[2][4 * 512 + lane * 8], s0, 0, 0, 0);
        s1 = __builtin_amdgcn_mfma_f32_16x16x32_bf16(a0, *(const short8*)&sW[1][1 * 512 + lane * 8], s1, 0, 0, 0);
        s1 = __builtin_amdgcn_mfma_f32_16x16x32_bf16(a1, *(const short8*)&sW[1][5 * 512 + lane * 8], s1, 0, 0, 0);
        s1 = __builtin_amdgcn_mfma_f32_16x16x32_bf16(ax0, *(const short8*)&sW[2][1 * 512 + lane * 8], s1, 0, 0, 0);
        s1 = __builtin_amdgcn_mfma_f32_16x16x32_bf16(ax1, *(const short8*)&sW[2][5 * 512 + lane * 8], s1, 0, 0, 0);
        s2 = __builtin_amdgcn_mfma_f32_16x16x32_bf16(a0, *(const short8*)&sW[1][2 * 512 + lane * 8], s2, 0, 0, 0);
        s2 = __builtin_amdgcn_mfma_f32_16x16x32_bf16(a1, *(const short8*)&sW[1][6 * 512 + lane * 8], s2, 0, 0, 0);
        s2 = __builtin_amdgcn_mfma_f32_16x16x32_bf16(ax0, *(const short8*)&sW[2][2 * 512 + lane * 8], s2, 0, 0, 0);
        s2 = __builtin_amdgcn_mfma_f32_16x16x32_bf16(ax1, *(const short8*)&sW[2][6 * 512 + lane * 8], s2, 0, 0, 0);
        s3 = __builtin_amdgcn_mfma_f32_16x16x32_bf16(a0, *(const short8*)&sW[1][3 * 512 + lane * 8], s3, 0, 0, 0);
        s3 = __builtin_amdgcn_mfma_f32_16x16x32_bf16(a1, *(const short8*)&sW[1][7 * 512 + lane * 8], s3, 0, 0, 0);
        s3 = __builtin_amdgcn_mfma_f32_16x16x32_bf16(ax0, *(const short8*)&sW[2][3 * 512 + lane * 8], s3, 0, 0, 0);
        s3 = __builtin_amdgcn_mfma_f32_16x16x32_bf16(ax1, *(const short8*)&sW[2][7 * 512 + lane * 8], s3, 0, 0, 0);
        floatx4 stl[4] = {s0, s1, s2, s3};
        #pragma unroll
        for (int nt = 0; nt < 4; ++nt) {
            float bs = bl1[nt * 16 + n16];
            #pragma unroll
            for (int r = 0; r < 4; ++r) {
                int node = base + quad * 4 + r;
                if (node < N)
                    buf1[(size_t)node * 128 + 64 + nt * 16 + n16] = f2bf(fmaxf(stl[nt][r] + bs, 0.f));
            }
        }
    }
}

// Gather for layer2: one wave per node, reads buf1 (g|s1 bf16).
// agg[node] = [g2in(64) | s2in(64)] bf16 (reuses layer1's agg buffer).
__global__ void k_gather2(const unsigned short* __restrict__ gs, const int* __restrict__ csr,
                          const int* __restrict__ offs, const int* __restrict__ cnt,
                          const float* __restrict__ dinv,
                          unsigned short* __restrict__ agg, int N) {
    int lane = threadIdx.x & 63;
    int wave = threadIdx.x >> 6;
    int node = blockIdx.x * 4 + wave;
    if (node >= N) return;
    int c = lane & 15, grp = lane >> 4;

    int st = offs[node];
    int cn = cnt[node];
    float di = dinv[node];

    float4 aC = {0.f, 0.f, 0.f, 0.f}, aD = {0.f, 0.f, 0.f, 0.f};
    for (int e = 0; e < cn; e += 8) {
        int i0 = e + grp, i1 = e + 4 + grp;
        float m0 = (i0 < cn) ? 1.f : 0.f;
        float m1 = (i1 < cn) ? 1.f : 0.f;
        int s0 = csr[st + (i0 < cn ? i0 : cn - 1)];
        int s1 = csr[st + (i1 < cn ? i1 : cn - 1)];
        float w0 = m0 * dinv[s0];
        float w1 = m1 * dinv[s1];
        const unsigned short* p0 = gs + (size_t)s0 * 128 + 4 * c;
        const unsigned short* p1 = gs + (size_t)s1 * 128 + 4 * c;
        ushort4 g0u = *(const ushort4*)p0;
        ushort4 g1u = *(const ushort4*)p1;
        ushort4 t0u = *(const ushort4*)(p0 + 64);
        ushort4 t1u = *(const ushort4*)(p1 + 64);
        aC.x += w0 * bf2f(g0u.x) + w1 * bf2f(g1u.x);
        aC.y += w0 * bf2f(g0u.y) + w1 * bf2f(g1u.y);
        aC.z += w0 * bf2f(g0u.z) + w1 * bf2f(g1u.z);
        aC.w += w0 * bf2f(g0u.w) + w1 * bf2f(g1u.w);
        aD.x += m0 * bf2f(t0u.x) + m1 * bf2f(t1u.x);
        aD.y += m0 * bf2f(t0u.y) + m1 * bf2f(t1u.y);
        aD.z += m0 * bf2f(t0u.z) + m1 * bf2f(t1u.z);
        aD.w += m0 * bf2f(t0u.w) + m1 * bf2f(t1u.w);
    }
    xor_reduce8(aC, aD);

    if (grp == 0) {
        ushort4 su = *(const ushort4*)&gs[(size_t)node * 128 + 4 * c];
        float d2 = di * di;
        ushort4 o;
        o.x = f2bf(di * aC.x + d2 * bf2f(su.x));
        o.y = f2bf(di * aC.y + d2 * bf2f(su.y));
        o.z = f2bf(di * aC.z + d2 * bf2f(su.z));
        o.w = f2bf(di * aC.w + d2 * bf2f(su.w));
        *(ushort4*)&agg[(size_t)node * 128 + 4 * c] = o;
    } else if (grp == 1) {
        float rn = 1.0f / fmaxf((float)cn, 1.0f);
        ushort4 o;
        o.x = f2bf(aD.x * rn); o.y = f2bf(aD.y * rn);
        o.z = f2bf(aD.z * rn); o.w = f2bf(aD.w * rn);
        *(ushort4*)&agg[(size_t)node * 128 + 64 + 4 * c] = o;
    }
}

// Layer-2 GEMMs + LN + concat-proj via MFMA. 512 thr = 8 waves, 16 nodes/wave.
// LN done in C-layout (row stats via 16-lane butterflies); LN'd cat written
// bf16 to per-wave LDS slot (stride 132 shorts: conflict-free b16 writes,
// 8B-aligned b64 frag reads), then proj via MFMA against staged Pw frags.
__launch_bounds__(512, 1)
__global__ void k_gemm2(const unsigned short* __restrict__ agg,
                        const unsigned short* __restrict__ buf1,
                        const float* __restrict__ W2, const float* __restrict__ b2,
                        const float* __restrict__ Wl2, const float* __restrict__ bl2,
                        const float* __restrict__ Wr2,
                        const float* __restrict__ lngG, const float* __restrict__ lnbG,
                        const float* __restrict__ lngS, const float* __restrict__ lnbS,
                        const float* __restrict__ Pw, const float* __restrict__ Pb,
                        float* __restrict__ out, int N) {
    alignas(16) __shared__ unsigned short sW[3][4096];   // 24 KB
    alignas(16) __shared__ unsigned short sP[8192];      // 16 KB
    alignas(16) __shared__ unsigned short sT[8][16 * 132];  // 33 KB
    int t = threadIdx.x;
    for (int i = t; i < 1536; i += 512) {
        int m = i >> 9;
        int rem = i & 511;
        int f = rem >> 6;
        int L = rem & 63;
        int kb = (f >> 2) * 32 + (L >> 4) * 8;
        int o = (f & 3) * 16 + (L & 15);
        const float* Wsrc = (m == 0) ? W2 : (m == 1) ? Wl2 : Wr2;
        unsigned short* dst = &sW[m][f * 512 + L * 8];
        #pragma unroll
        for (int j = 0; j < 8; ++j) dst[j] = f2bf(Wsrc[(kb + j) * 64 + o]);
    }
    for (int i = t; i < 1024; i += 512) {
        int f = i >> 6;
        int L = i & 63;
        int kb = (f >> 2) * 32 + (L >> 4) * 8;
        int o = (f & 3) * 16 + (L & 15);
        unsigned short* dst = &sP[f * 512 + L * 8];
        #pragma unroll
        for (int j = 0; j < 8; ++j) dst[j] = f2bf(Pw[(kb + j) * 64 + o]);
    }
    __syncthreads();

    int lane = t & 63;
    int wave = t >> 6;
    int quad = lane >> 4;
    int n16 = lane & 15;
    int base = blockIdx.x * 128 + wave * 16;
    if (base >= N) return;
    int nm = base + n16;
    if (nm >= N) nm = N - 1;
    const unsigned short* ar = agg + (size_t)nm * 128;
    const unsigned short* br = buf1 + (size_t)nm * 128;
    unsigned short* tw = &sT[wave][0];

    // ---- GCN branch: g2in @ W2, bias, LN, stage gln ----
    {
        short8 a0 = *(const short8*)(ar + quad * 8);
        short8 a1 = *(const short8*)(ar + 32 + quad * 8);
        floatx4 c0 = {0.f, 0.f, 0.f, 0.f}, c1 = c0, c2 = c0, c3 = c0;
        c0 = __builtin_amdgcn_mfma_f32_16x16x32_bf16(a0, *(const short8*)&sW[0][0 * 512 + lane * 8], c0, 0, 0, 0);
        c0 = __builtin_amdgcn_mfma_f32_16x16x32_bf16(a1, *(const short8*)&sW[0][4 * 512 + lane * 8], c0, 0, 0, 0);
        c1 = __builtin_amdgcn_mfma_f32_16x16x32_bf16(a0, *(const short8*)&sW[0][1 * 512 + lane * 8], c1, 0, 0, 0);
        c1 = __builtin_amdgcn_mfma_f32_16x16x32_bf16(a1, *(const short8*)&sW[0][5 * 512 + lane * 8], c1, 0, 0, 0);
        c2 = __builtin_amdgcn_mfma_f32_16x16x32_bf16(a0, *(const short8*)&sW[0][2 * 512 + lane * 8], c2, 0, 0, 0);
        c2 = __builtin_amdgcn_mfma_f32_16x16x32_bf16(a1, *(const short8*)&sW[0][6 * 512 + lane * 8], c2, 0, 0, 0);
        c3 = __builtin_amdgcn_mfma_f32_16x16x32_bf16(a0, *(const short8*)&sW[0][3 * 512 + lane * 8], c3, 0, 0, 0);
        c3 = __builtin_amdgcn_mfma_f32_16x16x32_bf16(a1, *(const short8*)&sW[0][7 * 512 + lane * 8], c3, 0, 0, 0);

        float bv0 = b2[n16], bv1 = b2[16 + n16], bv2 = b2[32 + n16], bv3 = b2[48 + n16];
        float gv0 = lngG[n16], gv1 = lngG[16 + n16], gv2 = lngG[32 + n16], gv3 = lngG[48 + n16];
        float ev0 = lnbG[n16], ev1 = lnbG[16 + n16], ev2 = lnbG[32 + n16], ev3 = lnbG[48 + n16];
        #pragma unroll
        for (int r = 0; r < 4; ++r) {
            float z0 = c0[r] + bv0, z1 = c1[r] + bv1, z2 = c2[r] + bv2, z3 = c3[r] + bv3;
            float s = red16(z0 + z1 + z2 + z3);
            float q = red16(z0 * z0 + z1 * z1 + z2 * z2 + z3 * z3);
            float mu = s * (1.0f / 64.0f);
            float var = fmaxf(q * (1.0f / 64.0f) - mu * mu, 0.0f);
            float rs = rsqrtf(var + 1e-5f);
            unsigned short* row = tw + (quad * 4 + r) * 132;
            row[n16]      = f2bf((z0 - mu) * rs * gv0 + ev0);
            row[16 + n16] = f2bf((z1 - mu) * rs * gv1 + ev1);
            row[32 + n16] = f2bf((z2 - mu) * rs * gv2 + ev2);
            row[48 + n16] = f2bf((z3 - mu) * rs * gv3 + ev3);
        }
    }

    // ---- SAGE branch: s2in @ Wl2 + s1 @ Wr2, bias, LN, stage sln ----
    {
        short8 a0 = *(const short8*)(ar + 64 + quad * 8);
        short8 a1 = *(const short8*)(ar + 96 + quad * 8);
        short8 v0 = *(const short8*)(br + 64 + quad * 8);
        short8 v1 = *(const short8*)(br + 96 + quad * 8);
        floatx4 c0 = {0.f, 0.f, 0.f, 0.f}, c1 = c0, c2 = c0, c3 = c0;
        c0 = __builtin_amdgcn_mfma_f32_16x16x32_bf16(a0, *(const short8*)&sW[1][0 * 512 + lane * 8], c0, 0, 0, 0);
        c0 = __builtin_amdgcn_mfma_f32_16x16x32_bf16(a1, *(const short8*)&sW[1][4 * 512 + lane * 8], c0, 0, 0, 0);
        c0 = __builtin_amdgcn_mfma_f32_16x16x32_bf16(v0, *(const short8*)&sW[2][0 * 512 + lane * 8], c0, 0, 0, 0);
        c0 = __builtin_amdgcn_mfma_f32_16x16x32_bf16(v1, *(const short8*)&sW[2][4 * 512 + lane * 8], c0, 0, 0, 0);
        c1 = __builtin_amdgcn_mfma_f32_16x16x32_bf16(a0, *(const short8*)&sW[1][1 * 512 + lane * 8], c1, 0, 0, 0);
        c1 = __builtin_amdgcn_mfma_f32_16x16x32_bf16(a1, *(const short8*)&sW[1][5 * 512 + lane * 8], c1, 0, 0, 0);
        c1 = __builtin_amdgcn_mfma_f32_16x16x32_bf16(v0, *(const short8*)&sW[2][1 * 512 + lane * 8], c1, 0, 0, 0);
        c1 = __builtin_amdgcn_mfma_f32_16x16x32_bf16(v1, *(const short8*)&sW[2][5 * 512 + lane * 8], c1, 0, 0, 0);
        c2 = __builtin_amdgcn_mfma_f32_16x16x32_bf16(a0, *(const short8*)&sW[1][2 * 512 + lane * 8], c2, 0, 0, 0);
        c2 = __builtin_amdgcn_mfma_f32_16x16x32_bf16(a1, *(const short8*)&sW[1][6 * 512 + lane * 8], c2, 0, 0, 0);
        c2 = __builtin_amdgcn_mfma_f32_16x16x32_bf16(v0, *(const short8*)&sW[2][2 * 512 + lane * 8], c2, 0, 0, 0);
        c2 = __builtin_amdgcn_mfma_f32_16x16x32_bf16(v1, *(const short8*)&sW[2][6 * 512 + lane * 8], c2, 0, 0, 0);
        c3 = __builtin_amdgcn_mfma_f32_16x16x32_bf16(a0, *(const short8*)&sW[1][3 * 512 + lane * 8], c3, 0, 0, 0);
        c3 = __builtin_amdgcn_mfma_f32_16x16x32_bf16(a1, *(const short8*)&sW[1][7 * 512 + lane * 8], c3, 0, 0, 0);
        c3 = __builtin_amdgcn_mfma_f32_16x16x32_bf16(v0, *(const short8*)&sW[2][3 * 512 + lane * 8], c3, 0, 0, 0);
        c3 = __builtin_amdgcn_mfma_f32_16x16x32_bf16(v1, *(const short8*)&sW[2][7 * 512 + lane * 8], c3, 0, 0, 0);

        float bv0 = bl2[n16], bv1 = bl2[16 + n16], bv2 = bl2[32 + n16], bv3 = bl2[48 + n16];
        float gv0 = lngS[n16], gv1 = lngS[16 + n16], gv2 = lngS[32 + n16], gv3 = lngS[48 + n16];
        float ev0 = lnbS[n16], ev1 = lnbS[16 + n16], ev2 = lnbS[32 + n16], ev3 = lnbS[48 + n16];
        #pragma unroll
        for (int r = 0; r < 4; ++r) {
            float z0 = c0[r] + bv0, z1 = c1[r] + bv1, z2 = c2[r] + bv2, z3 = c3[r] + bv3;
            float s = red16(z0 + z1 + z2 + z3);
            float q = red16(z0 * z0 + z1 * z1 + z2 * z2 + z3 * z3);
            float mu = s * (1.0f / 64.0f);
            float var = fmaxf(q * (1.0f / 64.0f) - mu * mu, 0.0f);
            float rs = rsqrtf(var + 1e-5f);
            unsigned short* row = tw + (quad * 4 + r) * 132 + 64;
            row[n16]      = f2bf((z0 - mu) * rs * gv0 + ev0);
            row[16 + n16] = f2bf((z1 - mu) * rs * gv1 + ev1);
            row[32 + n16] = f2bf((z2 - mu) * rs * gv2 + ev2);
            row[48 + n16] = f2bf((z3 - mu) * rs * gv3 + ev3);
        }
    }

    // ---- proj: cat(128) @ Pw(128x64) + Pb ----
    // A rows from sT (wave-local; compiler orders via lgkmcnt). b64 pairs.
    floatx4 o0 = {0.f, 0.f, 0.f, 0.f}, o1 = o0, o2 = o0, o3 = o0;
    #pragma unroll
    for (int ks = 0; ks < 4; ++ks) {
        const unsigned short* ap = tw + n16 * 132 + ks * 32 + quad * 8;
        short4v lo = *(const short4v*)ap;
        short4v hi = *(const short4v*)(ap + 4);
        short8 af;
        af[0] = lo[0]; af[1] = lo[1]; af[2] = lo[2]; af[3] = lo[3];
        af[4] = hi[0]; af[5] = hi[1]; af[6] = hi[2]; af[7] = hi[3];
        o0 = __builtin_amdgcn_mfma_f32_16x16x32_bf16(af, *(const short8*)&sP[(ks * 4 + 0) * 512 + lane * 8], o0, 0, 0, 0);
        o1 = __builtin_amdgcn_mfma_f32_16x16x32_bf16(af, *(const short8*)&sP[(ks * 4 + 1) * 512 + lane * 8], o1, 0, 0, 0);
        o2 = __builtin_amdgcn_mfma_f32_16x16x32_bf16(af, *(const short8*)&sP[(ks * 4 + 2) * 512 + lane * 8], o2, 0, 0, 0);
        o3 = __builtin_amdgcn_mfma_f32_16x16x32_bf16(af, *(const short8*)&sP[(ks * 4 + 3) * 512 + lane * 8], o3, 0, 0, 0);
    }
    float p0 = Pb[n16], p1 = Pb[16 + n16], p2 = Pb[32 + n16], p3 = Pb[48 + n16];
    floatx4 ot[4] = {o0, o1, o2, o3};
    float pv[4] = {p0, p1, p2, p3};
    #pragma unroll
    for (int nt = 0; nt < 4; ++nt) {
        #pragma unroll
        for (int r = 0; r < 4; ++r) {
            int node = base + quad * 4 + r;
            if (node < N) out[(size_t)node * 64 + nt * 16 + n16] = ot[nt][r] + pv[nt];
        }
    }
}

extern "C" void kernel_launch(void* const* d_in, const int* in_sizes, int n_in,
                              void* d_out, int out_size, void* d_ws, size_t ws_size,
                              hipStream_t stream) {
    const float* x        = (const float*)d_in[0];
    const int*   ei       = (const int*)d_in[1];
    const float* gcn_w1   = (const float*)d_in[2];
    const float* gcn_b1   = (const float*)d_in[3];
    const float* gcn_w2   = (const float*)d_in[4];
    const float* gcn_b2   = (const float*)d_in[5];
    const float* sage_wl1 = (const float*)d_in[6];
    const float* sage_bl1 = (const float*)d_in[7];
    const float* sage_wr1 = (const float*)d_in[8];
    const float* sage_wl2 = (const float*)d_in[9];
    const float* sage_bl2 = (const float*)d_in[10];
    const float* sage_wr2 = (const float*)d_in[11];
    const float* gcn_ln_g = (const float*)d_in[12];
    const float* gcn_ln_b = (const float*)d_in[13];
    const float* sage_ln_g = (const float*)d_in[14];
    const float* sage_ln_b = (const float*)d_in[15];
    const float* proj_w   = (const float*)d_in[16];
    const float* proj_b   = (const float*)d_in[17];
    float* out = (float*)d_out;

    const int N = in_sizes[0] / 64;
    const int E = in_sizes[1] / 2;
    const int B = (N + SCAN_CHUNK - 1) / SCAN_CHUNK;

    char* w = (char*)d_ws;
    size_t off = 0;
    auto alloc = [&](size_t bytes) -> void* {
        void* p = w + off;
        off = (off + bytes + 255) & ~(size_t)255;
        return p;
    };
    int*            cnt       = (int*)alloc((size_t)N * 4);
    int*            offs      = (int*)alloc((size_t)N * 4);
    int*            cursor    = (int*)alloc((size_t)N * 4);
    float*          dinv      = (float*)alloc((size_t)N * 4);
    int*            blockSums = (int*)alloc((size_t)(B + 1) * 4);
    int*            csr       = (int*)alloc((size_t)E * 4);
    unsigned short* agg       = (unsigned short*)alloc((size_t)N * 128 * 2);  // layer1 agg, reused as layer2 agg
    unsigned short* buf1      = (unsigned short*)alloc((size_t)N * 128 * 2);  // g|s1 bf16
    (void)ws_size; (void)n_in; (void)out_size;

    hipMemsetAsync(cnt, 0, (size_t)N * 4, stream);
    hipMemsetAsync(cursor, 0, (size_t)N * 4, stream);

    int e4Blocks = ((E + 3) / 4 + 255) / 256;
    k_count<<<e4Blocks, 256, 0, stream>>>(ei, E, cnt);
    k_scan_reduce<<<B, 256, 0, stream>>>(cnt, N, blockSums);
    k_scan_spine<<<1, 64, 0, stream>>>(blockSums, B);
    k_scan_write<<<B, 256, 0, stream>>>(cnt, N, blockSums, offs, dinv);
    k_fill<<<e4Blocks, 256, 0, stream>>>(ei, E, offs, cursor, csr);

    k_gather1<<<(N + 3) / 4, 256, 0, stream>>>(x, csr, offs, cnt, dinv, agg, N);
    k_gemm1<<<(N + 127) / 128, 512, 0, stream>>>(agg, x, gcn_w1, gcn_b1,
                                                 sage_wl1, sage_bl1, sage_wr1, buf1, N);
    k_gather2<<<(N + 3) / 4, 256, 0, stream>>>(buf1, csr, offs, cnt, dinv, agg, N);
    k_gemm2<<<(N + 127) / 128, 512, 0, stream>>>(agg, buf1, gcn_w2, gcn_b2,
                                                 sage_wl2, sage_bl2, sage_wr2,
                                                 gcn_ln_g, gcn_ln_b, sage_ln_g, sage_ln_b,
                                                 proj_w, proj_b, out, N);
}

// Round 9
// 344.238 us; speedup vs baseline: 13.1404x; 1.1355x over previous
//
#include <hip/hip_runtime.h>

// N=100000 nodes, E=1250000 edges, all dims 64.
// R9: k_fill was the top dispatch (85us): atomic+dependent-scatter chain.
// Fix: k_count's atomicAdd return value IS the per-dst rank -> store it
// (buffer aliased onto agg, dead until gather1); k_fill becomes atomic-free.
// Also: x pre-converted to bf16 (ws-guarded) -> gather1 reads 128B/edge
// instead of 256B, gemm1 loads x A-frags directly as short8.

#define SCAN_CHUNK 2048

typedef __attribute__((ext_vector_type(8))) short short8;   // 8 bf16 = 4 VGPRs
typedef __attribute__((ext_vector_type(4))) short short4v;  // 4 bf16 = 2 VGPRs
typedef __attribute__((ext_vector_type(4))) float floatx4;  // MFMA C/D

__device__ __forceinline__ unsigned short f2bf(float f) {
    unsigned int u = __float_as_uint(f);
    unsigned int r = u + 0x7FFFu + ((u >> 16) & 1u);  // round-to-nearest-even
    return (unsigned short)(r >> 16);
}
__device__ __forceinline__ float bf2f(unsigned short h) {
    return __uint_as_float(((unsigned int)h) << 16);
}

// count + record per-edge rank (return of atomicAdd) -> atomic-free fill
__global__ void k_count(const int* __restrict__ ei, int E, int* __restrict__ cnt,
                        int* __restrict__ rank) {
    int i = blockIdx.x * blockDim.x + threadIdx.x;
    int e = i * 4;
    if (e + 4 <= E) {
        int4 d = *(const int4*)&ei[E + e];
        int4 r;
        r.x = atomicAdd(&cnt[d.x], 1);
        r.y = atomicAdd(&cnt[d.y], 1);
        r.z = atomicAdd(&cnt[d.z], 1);
        r.w = atomicAdd(&cnt[d.w], 1);
        *(int4*)&rank[e] = r;
    } else {
        for (int j = e; j < E; ++j) rank[j] = atomicAdd(&cnt[ei[E + j]], 1);
    }
}

__global__ void k_scan_reduce(const int* __restrict__ cnt, int N, int* __restrict__ blockSums) {
    __shared__ int lds[256];
    int base = blockIdx.x * SCAN_CHUNK;
    int t = threadIdx.x;
    int s = 0;
    for (int j = 0; j < 8; ++j) {
        int idx = base + t * 8 + j;
        if (idx < N) s += cnt[idx];
    }
    lds[t] = s;
    __syncthreads();
    for (int d = 128; d > 0; d >>= 1) {
        if (t < d) lds[t] += lds[t + d];
        __syncthreads();
    }
    if (t == 0) blockSums[blockIdx.x] = lds[0];
}

__global__ void k_scan_spine(int* __restrict__ blockSums, int B) {
    if (threadIdx.x == 0 && blockIdx.x == 0) {
        int run = 0;
        for (int b = 0; b < B; ++b) { int v = blockSums[b]; blockSums[b] = run; run += v; }
    }
}

__global__ void k_scan_write(const int* __restrict__ cnt, int N,
                             const int* __restrict__ blockSums,
                             int* __restrict__ offs, float* __restrict__ dinv) {
    __shared__ int lds[256];
    int base = blockIdx.x * SCAN_CHUNK;
    int t = threadIdx.x;
    int v[8];
    int s = 0;
    for (int j = 0; j < 8; ++j) {
        int idx = base + t * 8 + j;
        v[j] = (idx < N) ? cnt[idx] : 0;
        s += v[j];
    }
    lds[t] = s;
    __syncthreads();
    for (int d = 1; d < 256; d <<= 1) {
        int x = (t >= d) ? lds[t - d] : 0;
        __syncthreads();
        lds[t] += x;
        __syncthreads();
    }
    int excl = (t == 0) ? 0 : lds[t - 1];
    int run = blockSums[blockIdx.x] + excl;
    for (int j = 0; j < 8; ++j) {
        int idx = base + t * 8 + j;
        if (idx < N) {
            offs[idx] = run;
            run += v[j];
            dinv[idx] = rsqrtf((float)v[j] + 1.0f);
        }
    }
}

// atomic-free fill: pos = offs[dst] + rank[e]
__global__ void k_fill(const int* __restrict__ ei, int E, const int* __restrict__ offs,
                       const int* __restrict__ rank, int* __restrict__ csr) {
    int i = blockIdx.x * blockDim.x + threadIdx.x;
    int e = i * 4;
    if (e + 4 <= E) {
        int4 s = *(const int4*)&ei[e];
        int4 d = *(const int4*)&ei[E + e];
        int4 r = *(const int4*)&rank[e];
        csr[offs[d.x] + r.x] = s.x;
        csr[offs[d.y] + r.y] = s.y;
        csr[offs[d.z] + r.z] = s.z;
        csr[offs[d.w] + r.w] = s.w;
    } else {
        for (int j = e; j < E; ++j) csr[offs[ei[E + j]] + rank[j]] = ei[j];
    }
}

__global__ void k_xtobf16(const float* __restrict__ x, unsigned short* __restrict__ xb, int total) {
    int i = blockIdx.x * blockDim.x + threadIdx.x;
    int e = i * 8;
    if (e + 8 <= total) {
        float4 a = *(const float4*)&x[e];
        float4 b = *(const float4*)&x[e + 4];
        short8 o;
        o[0] = (short)f2bf(a.x); o[1] = (short)f2bf(a.y);
        o[2] = (short)f2bf(a.z); o[3] = (short)f2bf(a.w);
        o[4] = (short)f2bf(b.x); o[5] = (short)f2bf(b.y);
        o[6] = (short)f2bf(b.z); o[7] = (short)f2bf(b.w);
        *(short8*)&xb[e] = o;
    } else {
        for (int j = e; j < total; ++j) xb[j] = f2bf(x[j]);
    }
}

__device__ __forceinline__ void xor_reduce8(float4& a, float4& b) {
    a.x += __shfl_xor(a.x, 16, 64); a.y += __shfl_xor(a.y, 16, 64);
    a.z += __shfl_xor(a.z, 16, 64); a.w += __shfl_xor(a.w, 16, 64);
    b.x += __shfl_xor(b.x, 16, 64); b.y += __shfl_xor(b.y, 16, 64);
    b.z += __shfl_xor(b.z, 16, 64); b.w += __shfl_xor(b.w, 16, 64);
    a.x += __shfl_xor(a.x, 32, 64); a.y += __shfl_xor(a.y, 32, 64);
    a.z += __shfl_xor(a.z, 32, 64); a.w += __shfl_xor(a.w, 32, 64);
    b.x += __shfl_xor(b.x, 32, 64); b.y += __shfl_xor(b.y, 32, 64);
    b.z += __shfl_xor(b.z, 32, 64); b.w += __shfl_xor(b.w, 32, 64);
}

__device__ __forceinline__ float red16(float v) {
    v += __shfl_xor(v, 1, 64);
    v += __shfl_xor(v, 2, 64);
    v += __shfl_xor(v, 4, 64);
    v += __shfl_xor(v, 8, 64);
    return v;
}

// Gather layer1 from bf16 x (128B/edge). agg[node] = [gin|sin] bf16.
__global__ void k_gather1_bf(const unsigned short* __restrict__ xb, const int* __restrict__ csr,
                             const int* __restrict__ offs, const int* __restrict__ cnt,
                             const float* __restrict__ dinv,
                             unsigned short* __restrict__ agg, int N) {
    int lane = threadIdx.x & 63;
    int wave = threadIdx.x >> 6;
    int node = blockIdx.x * 4 + wave;
    if (node >= N) return;
    int c = lane & 15, grp = lane >> 4;

    int st = offs[node];
    int cn = cnt[node];
    float di = dinv[node];

    float4 aA = {0.f, 0.f, 0.f, 0.f}, aB = {0.f, 0.f, 0.f, 0.f};
    for (int e = 0; e < cn; e += 8) {
        int i0 = e + grp, i1 = e + 4 + grp;
        float m0 = (i0 < cn) ? 1.f : 0.f;
        float m1 = (i1 < cn) ? 1.f : 0.f;
        int s0 = csr[st + (i0 < cn ? i0 : cn - 1)];
        int s1 = csr[st + (i1 < cn ? i1 : cn - 1)];
        float w0 = m0 * dinv[s0];
        float w1 = m1 * dinv[s1];
        ushort4 u0 = *(const ushort4*)&xb[(size_t)s0 * 64 + 4 * c];
        ushort4 u1 = *(const ushort4*)&xb[(size_t)s1 * 64 + 4 * c];
        float4 v0 = {bf2f(u0.x), bf2f(u0.y), bf2f(u0.z), bf2f(u0.w)};
        float4 v1 = {bf2f(u1.x), bf2f(u1.y), bf2f(u1.z), bf2f(u1.w)};
        aA.x += w0 * v0.x + w1 * v1.x; aA.y += w0 * v0.y + w1 * v1.y;
        aA.z += w0 * v0.z + w1 * v1.z; aA.w += w0 * v0.w + w1 * v1.w;
        aB.x += m0 * v0.x + m1 * v1.x; aB.y += m0 * v0.y + m1 * v1.y;
        aB.z += m0 * v0.z + m1 * v1.z; aB.w += m0 * v0.w + m1 * v1.w;
    }
    xor_reduce8(aA, aB);

    if (grp == 0) {
        ushort4 su = *(const ushort4*)&xb[(size_t)node * 64 + 4 * c];
        float d2 = di * di;
        ushort4 o;
        o.x = f2bf(di * aA.x + d2 * bf2f(su.x));
        o.y = f2bf(di * aA.y + d2 * bf2f(su.y));
        o.z = f2bf(di * aA.z + d2 * bf2f(su.z));
        o.w = f2bf(di * aA.w + d2 * bf2f(su.w));
        *(ushort4*)&agg[(size_t)node * 128 + 4 * c] = o;
    } else if (grp == 1) {
        float rn = 1.0f / fmaxf((float)cn, 1.0f);
        ushort4 o;
        o.x = f2bf(aB.x * rn); o.y = f2bf(aB.y * rn);
        o.z = f2bf(aB.z * rn); o.w = f2bf(aB.w * rn);
        *(ushort4*)&agg[(size_t)node * 128 + 64 + 4 * c] = o;
    }
}

// fp32 fallback (used only if ws too small for xb)
__global__ void k_gather1_f32(const float* __restrict__ x, const int* __restrict__ csr,
                              const int* __restrict__ offs, const int* __restrict__ cnt,
                              const float* __restrict__ dinv,
                              unsigned short* __restrict__ agg, int N) {
    int lane = threadIdx.x & 63;
    int wave = threadIdx.x >> 6;
    int node = blockIdx.x * 4 + wave;
    if (node >= N) return;
    int c = lane & 15, grp = lane >> 4;

    int st = offs[node];
    int cn = cnt[node];
    float di = dinv[node];

    float4 aA = {0.f, 0.f, 0.f, 0.f}, aB = {0.f, 0.f, 0.f, 0.f};
    for (int e = 0; e < cn; e += 8) {
        int i0 = e + grp, i1 = e + 4 + grp;
        float m0 = (i0 < cn) ? 1.f : 0.f;
        float m1 = (i1 < cn) ? 1.f : 0.f;
        int s0 = csr[st + (i0 < cn ? i0 : cn - 1)];
        int s1 = csr[st + (i1 < cn ? i1 : cn - 1)];
        float w0 = m0 * dinv[s0];
        float w1 = m1 * dinv[s1];
        float4 v0 = *(const float4*)&x[(size_t)s0 * 64 + 4 * c];
        float4 v1 = *(const float4*)&x[(size_t)s1 * 64 + 4 * c];
        aA.x += w0 * v0.x + w1 * v1.x; aA.y += w0 * v0.y + w1 * v1.y;
        aA.z += w0 * v0.z + w1 * v1.z; aA.w += w0 * v0.w + w1 * v1.w;
        aB.x += m0 * v0.x + m1 * v1.x; aB.y += m0 * v0.y + m1 * v1.y;
        aB.z += m0 * v0.z + m1 * v1.z; aB.w += m0 * v0.w + m1 * v1.w;
    }
    xor_reduce8(aA, aB);

    if (grp == 0) {
        float4 sq = *(const float4*)&x[(size_t)node * 64 + 4 * c];
        float d2 = di * di;
        ushort4 o;
        o.x = f2bf(di * aA.x + d2 * sq.x); o.y = f2bf(di * aA.y + d2 * sq.y);
        o.z = f2bf(di * aA.z + d2 * sq.z); o.w = f2bf(di * aA.w + d2 * sq.w);
        *(ushort4*)&agg[(size_t)node * 128 + 4 * c] = o;
    } else if (grp == 1) {
        float rn = 1.0f / fmaxf((float)cn, 1.0f);
        ushort4 o;
        o.x = f2bf(aB.x * rn); o.y = f2bf(aB.y * rn);
        o.z = f2bf(aB.z * rn); o.w = f2bf(aB.w * rn);
        *(ushort4*)&agg[(size_t)node * 128 + 64 + 4 * c] = o;
    }
}

// Layer-1 GEMMs via MFMA. use_xb selects bf16 or fp32 x source (uniform).
__launch_bounds__(512, 1)
__global__ void k_gemm1(const unsigned short* __restrict__ agg,
                        const unsigned short* __restrict__ xb,
                        const float* __restrict__ xf, int use_xb,
                        const float* __restrict__ W1, const float* __restrict__ b1,
                        const float* __restrict__ Wl1, const float* __restrict__ bl1,
                        const float* __restrict__ Wr1,
                        unsigned short* __restrict__ buf1, int N) {
    alignas(16) __shared__ unsigned short sW[3][4096];
    int t = threadIdx.x;
    for (int i = t; i < 1536; i += 512) {
        int m = i >> 9;
        int rem = i & 511;
        int f = rem >> 6;
        int L = rem & 63;
        int kb = (f >> 2) * 32 + (L >> 4) * 8;
        int o = (f & 3) * 16 + (L & 15);
        const float* Wsrc = (m == 0) ? W1 : (m == 1) ? Wl1 : Wr1;
        unsigned short* dst = &sW[m][f * 512 + L * 8];
        #pragma unroll
        for (int j = 0; j < 8; ++j) dst[j] = f2bf(Wsrc[(kb + j) * 64 + o]);
    }
    __syncthreads();

    int lane = t & 63;
    int wave = t >> 6;
    int quad = lane >> 4;
    int n16 = lane & 15;
    int base = blockIdx.x * 128 + wave * 16;
    if (base >= N) return;

    int nm = base + n16;
    if (nm >= N) nm = N - 1;
    const unsigned short* ar = agg + (size_t)nm * 128;

    {
        short8 a0 = *(const short8*)(ar + quad * 8);
        short8 a1 = *(const short8*)(ar + 32 + quad * 8);
        floatx4 g0 = {0.f, 0.f, 0.f, 0.f}, g1 = g0, g2 = g0, g3 = g0;
        g0 = __builtin_amdgcn_mfma_f32_16x16x32_bf16(a0, *(const short8*)&sW[0][0 * 512 + lane * 8], g0, 0, 0, 0);
        g0 = __builtin_amdgcn_mfma_f32_16x16x32_bf16(a1, *(const short8*)&sW[0][4 * 512 + lane * 8], g0, 0, 0, 0);
        g1 = __builtin_amdgcn_mfma_f32_16x16x32_bf16(a0, *(const short8*)&sW[0][1 * 512 + lane * 8], g1, 0, 0, 0);
        g1 = __builtin_amdgcn_mfma_f32_16x16x32_bf16(a1, *(const short8*)&sW[0][5 * 512 + lane * 8], g1, 0, 0, 0);
        g2 = __builtin_amdgcn_mfma_f32_16x16x32_bf16(a0, *(const short8*)&sW[0][2 * 512 + lane * 8], g2, 0, 0, 0);
        g2 = __builtin_amdgcn_mfma_f32_16x16x32_bf16(a1, *(const short8*)&sW[0][6 * 512 + lane * 8], g2, 0, 0, 0);
        g3 = __builtin_amdgcn_mfma_f32_16x16x32_bf16(a0, *(const short8*)&sW[0][3 * 512 + lane * 8], g3, 0, 0, 0);
        g3 = __builtin_amdgcn_mfma_f32_16x16x32_bf16(a1, *(const short8*)&sW[0][7 * 512 + lane * 8], g3, 0, 0, 0);
        floatx4 gt[4] = {g0, g1, g2, g3};
        #pragma unroll
        for (int nt = 0; nt < 4; ++nt) {
            float bg = b1[nt * 16 + n16];
            #pragma unroll
            for (int r = 0; r < 4; ++r) {
                int node = base + quad * 4 + r;
                if (node < N)
                    buf1[(size_t)node * 128 + nt * 16 + n16] = f2bf(fmaxf(gt[nt][r] + bg, 0.f));
            }
        }
    }

    {
        short8 a0 = *(const short8*)(ar + 64 + quad * 8);
        short8 a1 = *(const short8*)(ar + 96 + quad * 8);
        short8 ax0, ax1;
        if (use_xb) {
            ax0 = *(const short8*)&xb[(size_t)nm * 64 + quad * 8];
            ax1 = *(const short8*)&xb[(size_t)nm * 64 + 32 + quad * 8];
        } else {
            float4 xq0 = *(const float4*)&xf[(size_t)nm * 64 + quad * 8];
            float4 xq1 = *(const float4*)&xf[(size_t)nm * 64 + quad * 8 + 4];
            float4 xq2 = *(const float4*)&xf[(size_t)nm * 64 + 32 + quad * 8];
            float4 xq3 = *(const float4*)&xf[(size_t)nm * 64 + 32 + quad * 8 + 4];
            ax0[0] = (short)f2bf(xq0.x); ax0[1] = (short)f2bf(xq0.y);
            ax0[2] = (short)f2bf(xq0.z); ax0[3] = (short)f2bf(xq0.w);
            ax0[4] = (short)f2bf(xq1.x); ax0[5] = (short)f2bf(xq1.y);
            ax0[6] = (short)f2bf(xq1.z); ax0[7] = (short)f2bf(xq1.w);
            ax1[0] = (short)f2bf(xq2.x); ax1[1] = (short)f2bf(xq2.y);
            ax1[2] = (short)f2bf(xq2.z); ax1[3] = (short)f2bf(xq2.w);
            ax1[4] = (short)f2bf(xq3.x); ax1[5] = (short)f2bf(xq3.y);
            ax1[6] = (short)f2bf(xq3.z); ax1[7] = (short)f2bf(xq3.w);
        }

        floatx4 s0 = {0.f, 0.f, 0.f, 0.f}, s1 = s0, s2 = s0, s3 = s0;
        s0 = __builtin_amdgcn_mfma_f32_16x16x32_bf16(a0, *(const short8*)&sW[1][0 * 512 + lane * 8], s0, 0, 0, 0);
        s0 = __builtin_amdgcn_mfma_f32_16x16x32_bf16(a1, *(const short8*)&sW[1][4 * 512 + lane * 8], s0, 0, 0, 0);
        s0 = __builtin_amdgcn_mfma_f32_16x16x32_bf16(ax0, *(const short8*)&sW[2][0 * 512 + lane * 8], s0, 0, 0, 0);
        s0 = __builtin_amdgcn_mfma_f32_16x16x32_bf16(ax1, *(const short8*)&sW[2][4 * 512 + lane * 8], s0, 0, 0, 0);
        s1 = __builtin_amdgcn_mfma_f32_16x16x32_bf16(a0, *(const short8*)&sW[1][1 * 512 + lane * 8], s1, 0, 0, 0);
        s1 = __builtin_amdgcn_mfma_f32_16x16x32_bf16(a1, *(const short8*)&sW[1][5 * 512 + lane * 8], s1, 0, 0, 0);
        s1 = __builtin_amdgcn_mfma_f32_16x16x32_bf16(ax0, *(const short8*)&sW[2][1 * 512 + lane * 8], s1, 0, 0, 0);
        s1 = __builtin_amdgcn_mfma_f32_16x16x32_bf16(ax1, *(const short8*)&sW[2][5 * 512 + lane * 8], s1, 0, 0, 0);
        s2 = __builtin_amdgcn_mfma_f32_16x16x32_bf16(a0, *(const short8*)&sW[1][2 * 512 + lane * 8], s2, 0, 0, 0);
        s2 = __builtin_amdgcn_mfma_f32_16x16x32_bf16(a1, *(const short8*)&sW[1][6 * 512 + lane * 8], s2, 0, 0, 0);
        s2 = __builtin_amdgcn_mfma_f32_16x16x32_bf16(ax0, *(const short8*)&sW[2][2 * 512 + lane * 8], s2, 0, 0, 0);
        s2 = __builtin_amdgcn_mfma_f32_16x16x32_bf16(ax1, *(const short8*)&sW[2][6 * 512 + lane * 8], s2, 0, 0, 0);
        s3 = __builtin_amdgcn_mfma_f32_16x16x32_bf16(a0, *(const short8*)&sW[1][3 * 512 + lane * 8], s3, 0, 0, 0);
        s3 = __builtin_amdgcn_mfma_f32_16x16x32_bf16(a1, *(const short8*)&sW[1][7 * 512 + lane * 8], s3, 0, 0, 0);
        s3 = __builtin_amdgcn_mfma_f32_16x16x32_bf16(ax0, *(const short8*)&sW[2][3 * 512 + lane * 8], s3, 0, 0, 0);
        s3 = __builtin_amdgcn_mfma_f32_16x16x32_bf16(ax1, *(const short8*)&sW[2][7 * 512 + lane * 8], s3, 0, 0, 0);
        floatx4 stl[4] = {s0, s1, s2, s3};
        #pragma unroll
        for (int nt = 0; nt < 4; ++nt) {
            float bs = bl1[nt * 16 + n16];
            #pragma unroll
            for (int r = 0; r < 4; ++r) {
                int node = base + quad * 4 + r;
                if (node < N)
                    buf1[(size_t)node * 128 + 64 + nt * 16 + n16] = f2bf(fmaxf(stl[nt][r] + bs, 0.f));
            }
        }
    }
}

// Gather for layer2 (reads buf1 g|s1 bf16), writes agg.
__global__ void k_gather2(const unsigned short* __restrict__ gs, const int* __restrict__ csr,
                          const int* __restrict__ offs, const int* __restrict__ cnt,
                          const float* __restrict__ dinv,
                          unsigned short* __restrict__ agg, int N) {
    int lane = threadIdx.x & 63;
    int wave = threadIdx.x >> 6;
    int node = blockIdx.x * 4 + wave;
    if (node >= N) return;
    int c = lane & 15, grp = lane >> 4;

    int st = offs[node];
    int cn = cnt[node];
    float di = dinv[node];

    float4 aC = {0.f, 0.f, 0.f, 0.f}, aD = {0.f, 0.f, 0.f, 0.f};
    for (int e = 0; e < cn; e += 8) {
        int i0 = e + grp, i1 = e + 4 + grp;
        float m0 = (i0 < cn) ? 1.f : 0.f;
        float m1 = (i1 < cn) ? 1.f : 0.f;
        int s0 = csr[st + (i0 < cn ? i0 : cn - 1)];
        int s1 = csr[st + (i1 < cn ? i1 : cn - 1)];
        float w0 = m0 * dinv[s0];
        float w1 = m1 * dinv[s1];
        const unsigned short* p0 = gs + (size_t)s0 * 128 + 4 * c;
        const unsigned short* p1 = gs + (size_t)s1 * 128 + 4 * c;
        ushort4 g0u = *(const ushort4*)p0;
        ushort4 g1u = *(const ushort4*)p1;
        ushort4 t0u = *(const ushort4*)(p0 + 64);
        ushort4 t1u = *(const ushort4*)(p1 + 64);
        aC.x += w0 * bf2f(g0u.x) + w1 * bf2f(g1u.x);
        aC.y += w0 * bf2f(g0u.y) + w1 * bf2f(g1u.y);
        aC.z += w0 * bf2f(g0u.z) + w1 * bf2f(g1u.z);
        aC.w += w0 * bf2f(g0u.w) + w1 * bf2f(g1u.w);
        aD.x += m0 * bf2f(t0u.x) + m1 * bf2f(t1u.x);
        aD.y += m0 * bf2f(t0u.y) + m1 * bf2f(t1u.y);
        aD.z += m0 * bf2f(t0u.z) + m1 * bf2f(t1u.z);
        aD.w += m0 * bf2f(t0u.w) + m1 * bf2f(t1u.w);
    }
    xor_reduce8(aC, aD);

    if (grp == 0) {
        ushort4 su = *(const ushort4*)&gs[(size_t)node * 128 + 4 * c];
        float d2 = di * di;
        ushort4 o;
        o.x = f2bf(di * aC.x + d2 * bf2f(su.x));
        o.y = f2bf(di * aC.y + d2 * bf2f(su.y));
        o.z = f2bf(di * aC.z + d2 * bf2f(su.z));
        o.w = f2bf(di * aC.w + d2 * bf2f(su.w));
        *(ushort4*)&agg[(size_t)node * 128 + 4 * c] = o;
    } else if (grp == 1) {
        float rn = 1.0f / fmaxf((float)cn, 1.0f);
        ushort4 o;
        o.x = f2bf(aD.x * rn); o.y = f2bf(aD.y * rn);
        o.z = f2bf(aD.z * rn); o.w = f2bf(aD.w * rn);
        *(ushort4*)&agg[(size_t)node * 128 + 64 + 4 * c] = o;
    }
}

// Layer-2 GEMMs + LN + concat-proj via MFMA (proven in R8).
__launch_bounds__(512, 1)
__global__ void k_gemm2(const unsigned short* __restrict__ agg,
                        const unsigned short* __restrict__ buf1,
                        const float* __restrict__ W2, const float* __restrict__ b2,
                        const float* __restrict__ Wl2, const float* __restrict__ bl2,
                        const float* __restrict__ Wr2,
                        const float* __restrict__ lngG, const float* __restrict__ lnbG,
                        const float* __restrict__ lngS, const float* __restrict__ lnbS,
                        const float* __restrict__ Pw, const float* __restrict__ Pb,
                        float* __restrict__ out, int N) {
    alignas(16) __shared__ unsigned short sW[3][4096];
    alignas(16) __shared__ unsigned short sP[8192];
    alignas(16) __shared__ unsigned short sT[8][16 * 132];
    int t = threadIdx.x;
    for (int i = t; i < 1536; i += 512) {
        int m = i >> 9;
        int rem = i & 511;
        int f = rem >> 6;
        int L = rem & 63;
        int kb = (f >> 2) * 32 + (L >> 4) * 8;
        int o = (f & 3) * 16 + (L & 15);
        const float* Wsrc = (m == 0) ? W2 : (m == 1) ? Wl2 : Wr2;
        unsigned short* dst = &sW[m][f * 512 + L * 8];
        #pragma unroll
        for (int j = 0; j < 8; ++j) dst[j] = f2bf(Wsrc[(kb + j) * 64 + o]);
    }
    for (int i = t; i < 1024; i += 512) {
        int f = i >> 6;
        int L = i & 63;
        int kb = (f >> 2) * 32 + (L >> 4) * 8;
        int o = (f & 3) * 16 + (L & 15);
        unsigned short* dst = &sP[f * 512 + L * 8];
        #pragma unroll
        for (int j = 0; j < 8; ++j) dst[j] = f2bf(Pw[(kb + j) * 64 + o]);
    }
    __syncthreads();

    int lane = t & 63;
    int wave = t >> 6;
    int quad = lane >> 4;
    int n16 = lane & 15;
    int base = blockIdx.x * 128 + wave * 16;
    if (base >= N) return;
    int nm = base + n16;
    if (nm >= N) nm = N - 1;
    const unsigned short* ar = agg + (size_t)nm * 128;
    const unsigned short* br = buf1 + (size_t)nm * 128;
    unsigned short* tw = &sT[wave][0];

    {
        short8 a0 = *(const short8*)(ar + quad * 8);
        short8 a1 = *(const short8*)(ar + 32 + quad * 8);
        floatx4 c0 = {0.f, 0.f, 0.f, 0.f}, c1 = c0, c2 = c0, c3 = c0;
        c0 = __builtin_amdgcn_mfma_f32_16x16x32_bf16(a0, *(const short8*)&sW[0][0 * 512 + lane * 8], c0, 0, 0, 0);
        c0 = __builtin_amdgcn_mfma_f32_16x16x32_bf16(a1, *(const short8*)&sW[0][4 * 512 + lane * 8], c0, 0, 0, 0);
        c1 = __builtin_amdgcn_mfma_f32_16x16x32_bf16(a0, *(const short8*)&sW[0][1 * 512 + lane * 8], c1, 0, 0, 0);
        c1 = __builtin_amdgcn_mfma_f32_16x16x32_bf16(a1, *(const short8*)&sW[0][5 * 512 + lane * 8], c1, 0, 0, 0);
        c2 = __builtin_amdgcn_mfma_f32_16x16x32_bf16(a0, *(const short8*)&sW[0][2 * 512 + lane * 8], c2, 0, 0, 0);
        c2 = __builtin_amdgcn_mfma_f32_16x16x32_bf16(a1, *(const short8*)&sW[0][6 * 512 + lane * 8], c2, 0, 0, 0);
        c3 = __builtin_amdgcn_mfma_f32_16x16x32_bf16(a0, *(const short8*)&sW[0][3 * 512 + lane * 8], c3, 0, 0, 0);
        c3 = __builtin_amdgcn_mfma_f32_16x16x32_bf16(a1, *(const short8*)&sW[0][7 * 512 + lane * 8], c3, 0, 0, 0);

        float bv0 = b2[n16], bv1 = b2[16 + n16], bv2 = b2[32 + n16], bv3 = b2[48 + n16];
        float gv0 = lngG[n16], gv1 = lngG[16 + n16], gv2 = lngG[32 + n16], gv3 = lngG[48 + n16];
        float ev0 = lnbG[n16], ev1 = lnbG[16 + n16], ev2 = lnbG[32 + n16], ev3 = lnbG[48 + n16];
        #pragma unroll
        for (int r = 0; r < 4; ++r) {
            float z0 = c0[r] + bv0, z1 = c1[r] + bv1, z2 = c2[r] + bv2, z3 = c3[r] + bv3;
            float s = red16(z0 + z1 + z2 + z3);
            float q = red16(z0 * z0 + z1 * z1 + z2 * z2 + z3 * z3);
            float mu = s * (1.0f / 64.0f);
            float var = fmaxf(q * (1.0f / 64.0f) - mu * mu, 0.0f);
            float rs = rsqrtf(var + 1e-5f);
            unsigned short* row = tw + (quad * 4 + r) * 132;
            row[n16]      = f2bf((z0 - mu) * rs * gv0 + ev0);
            row[16 + n16] = f2bf((z1 - mu) * rs * gv1 + ev1);
            row[32 + n16] = f2bf((z2 - mu) * rs * gv2 + ev2);
            row[48 + n16] = f2bf((z3 - mu) * rs * gv3 + ev3);
        }
    }

    {
        short8 a0 = *(const short8*)(ar + 64 + quad * 8);
        short8 a1 = *(const short8*)(ar + 96 + quad * 8);
        short8 v0 = *(const short8*)(br + 64 + quad * 8);
        short8 v1 = *(const short8*)(br + 96 + quad * 8);
        floatx4 c0 = {0.f, 0.f, 0.f, 0.f}, c1 = c0, c2 = c0, c3 = c0;
        c0 = __builtin_amdgcn_mfma_f32_16x16x32_bf16(a0, *(const short8*)&sW[1][0 * 512 + lane * 8], c0, 0, 0, 0);
        c0 = __builtin_amdgcn_mfma_f32_16x16x32_bf16(a1, *(const short8*)&sW[1][4 * 512 + lane * 8], c0, 0, 0, 0);
        c0 = __builtin_amdgcn_mfma_f32_16x16x32_bf16(v0, *(const short8*)&sW[2][0 * 512 + lane * 8], c0, 0, 0, 0);
        c0 = __builtin_amdgcn_mfma_f32_16x16x32_bf16(v1, *(const short8*)&sW[2][4 * 512 + lane * 8], c0, 0, 0, 0);
        c1 = __builtin_amdgcn_mfma_f32_16x16x32_bf16(a0, *(const short8*)&sW[1][1 * 512 + lane * 8], c1, 0, 0, 0);
        c1 = __builtin_amdgcn_mfma_f32_16x16x32_bf16(a1, *(const short8*)&sW[1][5 * 512 + lane * 8], c1, 0, 0, 0);
        c1 = __builtin_amdgcn_mfma_f32_16x16x32_bf16(v0, *(const short8*)&sW[2][1 * 512 + lane * 8], c1, 0, 0, 0);
        c1 = __builtin_amdgcn_mfma_f32_16x16x32_bf16(v1, *(const short8*)&sW[2][5 * 512 + lane * 8], c1, 0, 0, 0);
        c2 = __builtin_amdgcn_mfma_f32_16x16x32_bf16(a0, *(const short8*)&sW[1][2 * 512 + lane * 8], c2, 0, 0, 0);
        c2 = __builtin_amdgcn_mfma_f32_16x16x32_bf16(a1, *(const short8*)&sW[1][6 * 512 + lane * 8], c2, 0, 0, 0);
        c2 = __builtin_amdgcn_mfma_f32_16x16x32_bf16(v0, *(const short8*)&sW[2][2 * 512 + lane * 8], c2, 0, 0, 0);
        c2 = __builtin_amdgcn_mfma_f32_16x16x32_bf16(v1, *(const short8*)&sW[2][6 * 512 + lane * 8], c2, 0, 0, 0);
        c3 = __builtin_amdgcn_mfma_f32_16x16x32_bf16(a0, *(const short8*)&sW[1][3 * 512 + lane * 8], c3, 0, 0, 0);
        c3 = __builtin_amdgcn_mfma_f32_16x16x32_bf16(a1, *(const short8*)&sW[1][7 * 512 + lane * 8], c3, 0, 0, 0);
        c3 = __builtin_amdgcn_mfma_f32_16x16x32_bf16(v0, *(const short8*)&sW[2][3 * 512 + lane * 8], c3, 0, 0, 0);
        c3 = __builtin_amdgcn_mfma_f32_16x16x32_bf16(v1, *(const short8*)&sW[2][7 * 512 + lane * 8], c3, 0, 0, 0);

        float bv0 = bl2[n16], bv1 = bl2[16 + n16], bv2 = bl2[32 + n16], bv3 = bl2[48 + n16];
        float gv0 = lngS[n16], gv1 = lngS[16 + n16], gv2 = lngS[32 + n16], gv3 = lngS[48 + n16];
        float ev0 = lnbS[n16], ev1 = lnbS[16 + n16], ev2 = lnbS[32 + n16], ev3 = lnbS[48 + n16];
        #pragma unroll
        for (int r = 0; r < 4; ++r) {
            float z0 = c0[r] + bv0, z1 = c1[r] + bv1, z2 = c2[r] + bv2, z3 = c3[r] + bv3;
            float s = red16(z0 + z1 + z2 + z3);
            float q = red16(z0 * z0 + z1 * z1 + z2 * z2 + z3 * z3);
            float mu = s * (1.0f / 64.0f);
            float var = fmaxf(q * (1.0f / 64.0f) - mu * mu, 0.0f);
            float rs = rsqrtf(var + 1e-5f);
            unsigned short* row = tw + (quad * 4 + r) * 132 + 64;
            row[n16]      = f2bf((z0 - mu) * rs * gv0 + ev0);
            row[16 + n16] = f2bf((z1 - mu) * rs * gv1 + ev1);
            row[32 + n16] = f2bf((z2 - mu) * rs * gv2 + ev2);
            row[48 + n16] = f2bf((z3 - mu) * rs * gv3 + ev3);
        }
    }

    floatx4 o0 = {0.f, 0.f, 0.f, 0.f}, o1 = o0, o2 = o0, o3 = o0;
    #pragma unroll
    for (int ks = 0; ks < 4; ++ks) {
        const unsigned short* ap = tw + n16 * 132 + ks * 32 + quad * 8;
        short4v lo = *(const short4v*)ap;
        short4v hi = *(const short4v*)(ap + 4);
        short8 af;
        af[0] = lo[0]; af[1] = lo[1]; af[2] = lo[2]; af[3] = lo[3];
        af[4] = hi[0]; af[5] = hi[1]; af[6] = hi[2]; af[7] = hi[3];
        o0 = __builtin_amdgcn_mfma_f32_16x16x32_bf16(af, *(const short8*)&sP[(ks * 4 + 0) * 512 + lane * 8], o0, 0, 0, 0);
        o1 = __builtin_amdgcn_mfma_f32_16x16x32_bf16(af, *(const short8*)&sP[(ks * 4 + 1) * 512 + lane * 8], o1, 0, 0, 0);
        o2 = __builtin_amdgcn_mfma_f32_16x16x32_bf16(af, *(const short8*)&sP[(ks * 4 + 2) * 512 + lane * 8], o2, 0, 0, 0);
        o3 = __builtin_amdgcn_mfma_f32_16x16x32_bf16(af, *(const short8*)&sP[(ks * 4 + 3) * 512 + lane * 8], o3, 0, 0, 0);
    }
    float p0 = Pb[n16], p1 = Pb[16 + n16], p2 = Pb[32 + n16], p3 = Pb[48 + n16];
    floatx4 ot[4] = {o0, o1, o2, o3};
    float pv[4] = {p0, p1, p2, p3};
    #pragma unroll
    for (int nt = 0; nt < 4; ++nt) {
        #pragma unroll
        for (int r = 0; r < 4; ++r) {
            int node = base + quad * 4 + r;
            if (node < N) out[(size_t)node * 64 + nt * 16 + n16] = ot[nt][r] + pv[nt];
        }
    }
}

extern "C" void kernel_launch(void* const* d_in, const int* in_sizes, int n_in,
                              void* d_out, int out_size, void* d_ws, size_t ws_size,
                              hipStream_t stream) {
    const float* x        = (const float*)d_in[0];
    const int*   ei       = (const int*)d_in[1];
    const float* gcn_w1   = (const float*)d_in[2];
    const float* gcn_b1   = (const float*)d_in[3];
    const float* gcn_w2   = (const float*)d_in[4];
    const float* gcn_b2   = (const float*)d_in[5];
    const float* sage_wl1 = (const float*)d_in[6];
    const float* sage_bl1 = (const float*)d_in[7];
    const float* sage_wr1 = (const float*)d_in[8];
    const float* sage_wl2 = (const float*)d_in[9];
    const float* sage_bl2 = (const float*)d_in[10];
    const float* sage_wr2 = (const float*)d_in[11];
    const float* gcn_ln_g = (const float*)d_in[12];
    const float* gcn_ln_b = (const float*)d_in[13];
    const float* sage_ln_g = (const float*)d_in[14];
    const float* sage_ln_b = (const float*)d_in[15];
    const float* proj_w   = (const float*)d_in[16];
    const float* proj_b   = (const float*)d_in[17];
    float* out = (float*)d_out;

    const int N = in_sizes[0] / 64;
    const int E = in_sizes[1] / 2;
    const int B = (N + SCAN_CHUNK - 1) / SCAN_CHUNK;

    char* w = (char*)d_ws;
    size_t off = 0;
    auto alloc = [&](size_t bytes) -> void* {
        void* p = w + off;
        off = (off + bytes + 255) & ~(size_t)255;
        return p;
    };
    int*            cnt       = (int*)alloc((size_t)N * 4);
    int*            offs      = (int*)alloc((size_t)N * 4);
    float*          dinv      = (float*)alloc((size_t)N * 4);
    int*            blockSums = (int*)alloc((size_t)(B + 1) * 4);
    int*            csr       = (int*)alloc((size_t)E * 4);
    unsigned short* agg       = (unsigned short*)alloc((size_t)N * 128 * 2);  // also aliases rank (dead before gather1)
    unsigned short* buf1      = (unsigned short*)alloc((size_t)N * 128 * 2);
    size_t off_noxb = off;
    unsigned short* xb        = (unsigned short*)alloc((size_t)N * 64 * 2);
    int use_xb = (off <= ws_size) ? 1 : 0;
    if (!use_xb) off = off_noxb;
    int* rank = (int*)agg;  // E*4 = 5MB <= 25.6MB agg region
    (void)n_in; (void)out_size;

    hipMemsetAsync(cnt, 0, (size_t)N * 4, stream);

    int e4Blocks = ((E + 3) / 4 + 255) / 256;
    k_count<<<e4Blocks, 256, 0, stream>>>(ei, E, cnt, rank);
    k_scan_reduce<<<B, 256, 0, stream>>>(cnt, N, blockSums);
    k_scan_spine<<<1, 64, 0, stream>>>(blockSums, B);
    k_scan_write<<<B, 256, 0, stream>>>(cnt, N, blockSums, offs, dinv);
    k_fill<<<e4Blocks, 256, 0, stream>>>(ei, E, offs, rank, csr);

    if (use_xb) {
        int xBlocks = ((N * 64 + 7) / 8 + 255) / 256;
        k_xtobf16<<<xBlocks, 256, 0, stream>>>(x, xb, N * 64);
        k_gather1_bf<<<(N + 3) / 4, 256, 0, stream>>>(xb, csr, offs, cnt, dinv, agg, N);
    } else {
        k_gather1_f32<<<(N + 3) / 4, 256, 0, stream>>>(x, csr, offs, cnt, dinv, agg, N);
    }
    k_gemm1<<<(N + 127) / 128, 512, 0, stream>>>(agg, xb, x, use_xb, gcn_w1, gcn_b1,
                                                 sage_wl1, sage_bl1, sage_wr1, buf1, N);
    k_gather2<<<(N + 3) / 4, 256, 0, stream>>>(buf1, csr, offs, cnt, dinv, agg, N);
    k_gemm2<<<(N + 127) / 128, 512, 0, stream>>>(agg, buf1, gcn_w2, gcn_b2,
                                                 sage_wl2, sage_bl2, sage_wr2,
                                                 gcn_ln_g, gcn_ln_b, sage_ln_g, sage_ln_b,
                                                 proj_w, proj_b, out, N);
}